// Round 9
// baseline (361.777 us; speedup 1.0000x reference)
//
#include <hip/hip_runtime.h>
#include <stdint.h>

typedef unsigned short u16;
typedef unsigned int u32;
typedef __attribute__((ext_vector_type(8))) __bf16 bf16x8;
typedef __attribute__((ext_vector_type(2))) __bf16 bf16x2;
typedef __attribute__((ext_vector_type(4))) float f32x4;
typedef __attribute__((ext_vector_type(16))) float f32x16;
typedef __attribute__((ext_vector_type(8))) u16 u16x8;
typedef __attribute__((ext_vector_type(4))) u32 u32x4;

#define Q_SCALE 0.1803368801111204f  /* 0.125 / ln(2): QK^T lands in log2 domain */

__device__ __forceinline__ float ex2(float x) { return __builtin_amdgcn_exp2f(x); }

__device__ __forceinline__ u16 f2bf(float f) {
  __bf16 h = (__bf16)f;
  return __builtin_bit_cast(u16, h);
}
__device__ __forceinline__ float bf2f(u16 u) {
  u32 x = ((u32)u) << 16;
  return __builtin_bit_cast(float, x);
}
__device__ __forceinline__ u32 pack2(float a, float b) {
  bf16x2 v; v.x = (__bf16)a; v.y = (__bf16)b;
  return __builtin_bit_cast(u32, v);
}
__device__ __forceinline__ void gl_lds16(const void* g, void* l) {
  __builtin_amdgcn_global_load_lds((const __attribute__((address_space(1))) void*)g,
                                   (__attribute__((address_space(3))) void*)l, 16, 0, 0);
}

// ------- 1+2 fused. z<4: weight transpose W[k][n]->WT[n][k] bf16; z==4: cvt
__global__ __launch_bounds__(256) void prep_kernel(const float* __restrict__ q,
                                                   const float* __restrict__ k,
                                                   const float* __restrict__ v,
                                                   u16* __restrict__ xdst,
                                                   const float* __restrict__ Wq,
                                                   const float* __restrict__ Wk,
                                                   const float* __restrict__ Wv,
                                                   const float* __restrict__ Wo,
                                                   u16* __restrict__ wcatT,
                                                   u16* __restrict__ woT) {
  __shared__ u16 tile[64][72];
  int z = blockIdx.z;
  int t = threadIdx.x;
  if (z == 4) {  // fp32 -> bf16 convert for q,k,v (3 * 4194304 elems)
    int b = blockIdx.y * 16 + blockIdx.x;  // 0..255
#pragma unroll 4
    for (int it = 0; it < 24; ++it) {
      size_t tt = (size_t)b * 6144 + it * 256 + t;
      size_t e = tt * 8;
      int which = (int)(e >> 22);
      const float* s = which == 0 ? q : which == 1 ? k : v;
      size_t off = e & 4194303;
      float4 a = *(const float4*)(s + off);
      float4 bb = *(const float4*)(s + off + 4);
      u16x8 o;
      o[0] = f2bf(a.x); o[1] = f2bf(a.y); o[2] = f2bf(a.z); o[3] = f2bf(a.w);
      o[4] = f2bf(bb.x); o[5] = f2bf(bb.y); o[6] = f2bf(bb.z); o[7] = f2bf(bb.w);
      *(u16x8*)(xdst + e) = o;
    }
    return;
  }
  const float* W = z == 0 ? Wq : z == 1 ? Wk : z == 2 ? Wv : Wo;
  int k0 = blockIdx.y * 64, n0 = blockIdx.x * 64;
  int r = t >> 2, c0 = (t & 3) * 16;
  const float* src = W + (size_t)(k0 + r) * 1024 + n0 + c0;
#pragma unroll
  for (int i = 0; i < 16; i += 4) {
    float4 x = *(const float4*)(src + i);
    tile[r][c0 + i] = f2bf(x.x); tile[r][c0 + i + 1] = f2bf(x.y);
    tile[r][c0 + i + 2] = f2bf(x.z); tile[r][c0 + i + 3] = f2bf(x.w);
  }
  __syncthreads();
  int n = t >> 2, kc = (t & 3) * 16;
  u16x8 o0, o1;
#pragma unroll
  for (int j = 0; j < 8; ++j) { o0[j] = tile[kc + j][n]; o1[j] = tile[kc + 8 + j][n]; }
  u16* dst = (z < 3) ? (wcatT + (size_t)z * 1048576 + (size_t)(n0 + n) * 1024 + k0 + kc)
                     : (woT + (size_t)(n0 + n) * 1024 + k0 + kc);
  *(u16x8*)dst = o0;
  *(u16x8*)(dst + 8) = o1;
}

// ---------------- 3. GEMM mode0: QKV proj, 128x128 tile, BK=32 --------------
__global__ __launch_bounds__(256) void gemm_bt(const u16* __restrict__ A,
                                               const u16* __restrict__ BT,
                                               u16* __restrict__ outBF,
                                               const float* __restrict__ b0,
                                               const float* __restrict__ b1,
                                               const float* __restrict__ b2) {
  __shared__ u16 As[2][4096];
  __shared__ u16 Bs[2][4096];
  int tid = threadIdx.x;
  int bid = blockIdx.y * 8 + blockIdx.x;
  int cpx = gridDim.y;
  int swz = (bid & 7) * cpx + (bid >> 3);
  int m0 = (swz >> 3) * 128, n0 = (swz & 7) * 128;
  const u16* bt = BT + (size_t)(m0 >> 12) * 1048576;
  int w = tid >> 6, l = tid & 63;
  int wr = w >> 1, wc = w & 1;
  f32x4 acc[4][4];
#pragma unroll
  for (int i = 0; i < 4; ++i)
#pragma unroll
    for (int j = 0; j < 4; ++j)
#pragma unroll
      for (int rr = 0; rr < 4; ++rr) acc[i][j][rr] = 0.f;

  auto stage = [&](int buf, int kt) {
#pragma unroll
    for (int i = 0; i < 2; ++i) {
      int id = i * 256 + tid;
      int r = id >> 2, cp = id & 3;
      int cl = cp ^ ((r ^ (r >> 2)) & 3);
      gl_lds16(A + (size_t)(m0 + r) * 1024 + kt * 32 + cl * 8, &As[buf][id * 8]);
      gl_lds16(bt + (size_t)(n0 + r) * 1024 + kt * 32 + cl * 8, &Bs[buf][id * 8]);
    }
  };
  stage(0, 0);
  __syncthreads();
  int sw = (l & 3) ^ ((l >> 2) & 3);
  int phys = (l >> 4) ^ sw;
  for (int kt = 0; kt < 32; ++kt) {
    int buf = kt & 1;
    if (kt < 31) stage(buf ^ 1, kt + 1);
    bf16x8 af[4], bfr[4];
#pragma unroll
    for (int mi = 0; mi < 4; ++mi) {
      int row = wr * 64 + mi * 16 + (l & 15);
      af[mi] = *(const bf16x8*)&As[buf][row * 32 + phys * 8];
    }
#pragma unroll
    for (int nj = 0; nj < 4; ++nj) {
      int rowb = wc * 64 + nj * 16 + (l & 15);
      bfr[nj] = *(const bf16x8*)&Bs[buf][rowb * 32 + phys * 8];
    }
#pragma unroll
    for (int mi = 0; mi < 4; ++mi)
#pragma unroll
      for (int nj = 0; nj < 4; ++nj)
        acc[mi][nj] = __builtin_amdgcn_mfma_f32_16x16x32_bf16(af[mi], bfr[nj],
                                                              acc[mi][nj], 0, 0, 0);
    __syncthreads();
  }
#pragma unroll
  for (int mi = 0; mi < 4; ++mi)
#pragma unroll
    for (int nj = 0; nj < 4; ++nj)
#pragma unroll
      for (int rr = 0; rr < 4; ++rr) {
        int row = m0 + wr * 64 + mi * 16 + (l >> 4) * 4 + rr;
        int col = n0 + wc * 64 + nj * 16 + (l & 15);
        float vv = acc[mi][nj][rr];
        int sec = row >> 12, orow = row & 4095;
        const float* bp = sec == 0 ? b0 : sec == 1 ? b1 : b2;
        vv += bp[col];
        if (sec == 0) vv *= Q_SCALE;   // fold 1/(8*ln2) into Q (exp2 softmax)
        outBF[(size_t)sec * 4194304 + (size_t)orow * 1024 + col] = f2bf(vv);
      }
}

// ---------------- 6. GEMM mode1: O-proj, 128x64 tile (512 blocks, 2/CU) ----
__global__ __launch_bounds__(256) void gemm_n64(const u16* __restrict__ A,
                                                const u16* __restrict__ BT,
                                                float* __restrict__ outF,
                                                const float* __restrict__ b0,
                                                const float* __restrict__ resid) {
  __shared__ u16 As[2][4096];
  __shared__ u16 Bs[2][2048];
  int tid = threadIdx.x;
  int bid = blockIdx.y * 8 + blockIdx.x;   // grid (8,64) = 512
  int swz = (bid & 7) * 64 + (bid >> 3);   // XCD chunk of 64
  int m0 = (swz >> 4) * 128, n0 = (swz & 15) * 64;
  int w = tid >> 6, l = tid & 63;
  int wr = w >> 1, wc = w & 1;
  f32x4 acc[4][2];
#pragma unroll
  for (int i = 0; i < 4; ++i)
#pragma unroll
    for (int j = 0; j < 2; ++j)
#pragma unroll
      for (int rr = 0; rr < 4; ++rr) acc[i][j][rr] = 0.f;

  auto stage = [&](int buf, int kt) {
#pragma unroll
    for (int i = 0; i < 2; ++i) {
      int id = i * 256 + tid;
      int r = id >> 2, cp = id & 3;
      int cl = cp ^ ((r ^ (r >> 2)) & 3);
      gl_lds16(A + (size_t)(m0 + r) * 1024 + kt * 32 + cl * 8, &As[buf][id * 8]);
    }
    {
      int id = tid;
      int r = id >> 2, cp = id & 3;
      int cl = cp ^ ((r ^ (r >> 2)) & 3);
      gl_lds16(BT + (size_t)(n0 + r) * 1024 + kt * 32 + cl * 8, &Bs[buf][id * 8]);
    }
  };
  stage(0, 0);
  __syncthreads();
  int sw = (l & 3) ^ ((l >> 2) & 3);
  int phys = (l >> 4) ^ sw;
  for (int kt = 0; kt < 32; ++kt) {
    int buf = kt & 1;
    if (kt < 31) stage(buf ^ 1, kt + 1);
    bf16x8 af[4], bfr[2];
#pragma unroll
    for (int mi = 0; mi < 4; ++mi) {
      int row = wr * 64 + mi * 16 + (l & 15);
      af[mi] = *(const bf16x8*)&As[buf][row * 32 + phys * 8];
    }
#pragma unroll
    for (int nj = 0; nj < 2; ++nj) {
      int rowb = wc * 32 + nj * 16 + (l & 15);
      bfr[nj] = *(const bf16x8*)&Bs[buf][rowb * 32 + phys * 8];
    }
#pragma unroll
    for (int mi = 0; mi < 4; ++mi)
#pragma unroll
      for (int nj = 0; nj < 2; ++nj)
        acc[mi][nj] = __builtin_amdgcn_mfma_f32_16x16x32_bf16(af[mi], bfr[nj],
                                                              acc[mi][nj], 0, 0, 0);
    __syncthreads();
  }
#pragma unroll
  for (int mi = 0; mi < 4; ++mi)
#pragma unroll
    for (int nj = 0; nj < 2; ++nj)
#pragma unroll
      for (int rr = 0; rr < 4; ++rr) {
        int row = m0 + wr * 64 + mi * 16 + (l >> 4) * 4 + rr;
        int col = n0 + wc * 32 + nj * 16 + (l & 15);
        outF[(size_t)row * 1024 + col] =
            acc[mi][nj][rr] + b0[col] + resid[(size_t)row * 1024 + col];
      }
}

// ---------------- 4. V transpose per head: vp[n][h*64+d] -> vt[h][d][n] ----
__global__ __launch_bounds__(256) void vtrans_kernel(const u16* __restrict__ vp,
                                                     u16* __restrict__ vt) {
  __shared__ u16 tile[64][72];
  int t = threadIdx.x;
  int n0 = blockIdx.x * 64, h = blockIdx.y;
  int r = t >> 2, c0 = (t & 3) * 16;
  u16x8 a = *(const u16x8*)(vp + (size_t)(n0 + r) * 1024 + h * 64 + c0);
  u16x8 b = *(const u16x8*)(vp + (size_t)(n0 + r) * 1024 + h * 64 + c0 + 8);
#pragma unroll
  for (int j = 0; j < 8; ++j) { tile[r][c0 + j] = a[j]; tile[r][c0 + 8 + j] = b[j]; }
  __syncthreads();
  int d = t >> 2, nc = (t & 3) * 16;
  u16x8 o0, o1;
#pragma unroll
  for (int j = 0; j < 8; ++j) { o0[j] = tile[nc + j][d]; o1[j] = tile[nc + 8 + j][d]; }
  size_t base = (size_t)(h * 64 + d) * 4096 + n0 + nc;
  *(u16x8*)(vt + base) = o0;
  *(u16x8*)(vt + base + 8) = o1;
}

// ---------------- 5. flash attention, KVBLK=32, 4 blocks/CU -----------------
// 8 waves = 512 thr, 128 q rows; waves 0-3 stream KV[0,2048), waves 4-7
// KV[2048,4096), own dbuf LDS each (32KB main loop -> 4 blocks/CU;
// launch_bounds(512,8) forces VGPR<=64 for 8 waves/SIMD = 100% occupancy).
// KVBLK=32: per tile 4 QK + 4 PV MFMA, 16 exp2, 2 P^T frags.
// Max-free exp2 softmax (sigma(s)~0.5 log2 units, offset cancels in O/l);
// l-sum on VALU; P^T frags via v_permlane32_swap_b32 (T12).
// K swizzle g=(r^(r>>3))&7 (128B rows, proven); V^T tile [64][32] has 64B
// rows -> g=((r>>1)^(r>>3))&3 (reaches the 4-lane/bank b128 floor).
__global__ __launch_bounds__(512, 8) void attn_kernel(const u16* __restrict__ qp,
                                                      const u16* __restrict__ kp,
                                                      const u16* __restrict__ vt,
                                                      u16* __restrict__ attout) {
  __shared__ u16 smem[19456];  // 38KB; loop uses [0,16384): [half][buf][K 2K|V 2K]
  int tid = threadIdx.x;
  int w = tid >> 6, l = tid & 63;
  int half = w >> 2, wl = w & 3;
  int hi = l >> 5, l31 = l & 31;
  int h = blockIdx.y, bx = blockIdx.x;
  int qrow = bx * 128 + wl * 32 + l31;
  bf16x8 qf[4];
#pragma unroll
  for (int ds = 0; ds < 4; ++ds)
    qf[ds] = *(const bf16x8*)(qp + (size_t)qrow * 1024 + h * 64 + ds * 16 + hi * 8);

  f32x16 accO[2];
#pragma unroll
  for (int r = 0; r < 16; ++r) { accO[0][r] = 0.f; accO[1][r] = 0.f; }
  float l_run = 0.f;

  u16* sbase = smem + half * 8192;
  int ht = (wl << 6) | l;  // half-local thread id, 0..255
  // stage sources, inverse-swizzled (rule #21)
  int rK = ht >> 3, cpK = ht & 7;
  int clK = cpK ^ ((rK ^ (rK >> 3)) & 7);
  const u16* srcK = kp + (size_t)(half * 2048 + rK) * 1024 + h * 64 + clK * 8;
  int dV = ht >> 2, cpV = ht & 3;
  int clV = cpV ^ (((dV >> 1) ^ (dV >> 3)) & 3);
  const u16* srcV = vt + (size_t)(h * 64 + dV) * 4096 + half * 2048 + clV * 8;
  int dstK = ht * 8, dstV = 2048 + ht * 8;
  auto stage = [&](int buf, int kt) {
    u16* b = sbase + buf * 4096;
    gl_lds16(srcK + (size_t)kt * 32768, b + dstK);
    gl_lds16(srcV + kt * 32, b + dstV);
  };
  stage(0, 0);
  __syncthreads();

  int gK = (l31 ^ (l31 >> 3)) & 7;
  int gV = ((l31 >> 1) ^ (l31 >> 3)) & 3;  // same value for row 32+l31

  for (int kt = 0; kt < 64; ++kt) {
    int buf = kt & 1;
    if (kt < 63) stage(buf ^ 1, kt + 1);
    const u16* Kt = sbase + buf * 4096;
    const u16* Vt = Kt + 2048;

    // S^T = K @ Q^T (32 kv x 32 q), log2 domain (Q pre-scaled)
    f32x16 accS;
#pragma unroll
    for (int r = 0; r < 16; ++r) accS[r] = 0.f;
    __builtin_amdgcn_s_setprio(1);
#pragma unroll
    for (int ds = 0; ds < 4; ++ds) {
      bf16x8 kf = *(const bf16x8*)(Kt + l31 * 64 + ((2 * ds + hi) ^ gK) * 8);
      accS = __builtin_amdgcn_mfma_f32_32x32x16_bf16(kf, qf[ds], accS, 0, 0, 0);
    }
    __builtin_amdgcn_s_setprio(0);

    // p = exp2(s) directly; accumulate l partials on VALU while packing
    u32 pku[8];
    float s0 = 0.f, s1 = 0.f, s2 = 0.f, s3 = 0.f;
#pragma unroll
    for (int qd = 0; qd < 8; ++qd) {
      float a = ex2(accS[2 * qd]);
      float b = ex2(accS[2 * qd + 1]);
      if (qd & 1) { s2 += a; s3 += b; } else { s0 += a; s1 += b; }
      pku[qd] = pack2(a, b);
    }
    float t1 = (s0 + s1) + (s2 + s3);
    t1 += __shfl_xor(t1, 32, 64);
    l_run += t1;

    // assemble P^T B-frags via permlane32_swap (A_hi <-> B_lo)
    bf16x8 pb0, pb1;
    {
      u32 a0 = pku[0], c0 = pku[2], a1 = pku[1], c1 = pku[3];
      asm("v_permlane32_swap_b32 %0, %1" : "+v"(a0), "+v"(c0));
      asm("v_permlane32_swap_b32 %0, %1" : "+v"(a1), "+v"(c1));
      u32x4 fr; fr[0] = a0; fr[1] = a1; fr[2] = c0; fr[3] = c1;
      pb0 = __builtin_bit_cast(bf16x8, fr);
      u32 a2 = pku[4], c2 = pku[6], a3 = pku[5], c3 = pku[7];
      asm("v_permlane32_swap_b32 %0, %1" : "+v"(a2), "+v"(c2));
      asm("v_permlane32_swap_b32 %0, %1" : "+v"(a3), "+v"(c3));
      u32x4 fr2; fr2[0] = a2; fr2[1] = a3; fr2[2] = c2; fr2[3] = c3;
      pb1 = __builtin_bit_cast(bf16x8, fr2);
    }
    // O^T += V^T @ P^T
    __builtin_amdgcn_s_setprio(1);
    {
      bf16x8 vf;
      vf = *(const bf16x8*)(Vt + l31 * 32 + ((0 + hi) ^ gV) * 8);
      accO[0] = __builtin_amdgcn_mfma_f32_32x32x16_bf16(vf, pb0, accO[0], 0, 0, 0);
      vf = *(const bf16x8*)(Vt + l31 * 32 + ((2 + hi) ^ gV) * 8);
      accO[0] = __builtin_amdgcn_mfma_f32_32x32x16_bf16(vf, pb1, accO[0], 0, 0, 0);
      vf = *(const bf16x8*)(Vt + (32 + l31) * 32 + ((0 + hi) ^ gV) * 8);
      accO[1] = __builtin_amdgcn_mfma_f32_32x32x16_bf16(vf, pb0, accO[1], 0, 0, 0);
      vf = *(const bf16x8*)(Vt + (32 + l31) * 32 + ((2 + hi) ^ gV) * 8);
      accO[1] = __builtin_amdgcn_mfma_f32_32x32x16_bf16(vf, pb1, accO[1], 0, 0, 0);
    }
    __builtin_amdgcn_s_setprio(0);
    __syncthreads();
  }

  // -------- cross-half combine: O = (O_A + O_B) / (l_A + l_B) --------
  // pO[half][q 128][72 u16] (bf16, unnormalized), ml[half][q 128] f32
  u16* pO = smem;
  float* ml = (float*)(smem + 18432);
  int q = wl * 32 + l31;
#pragma unroll
  for (int mto = 0; mto < 2; ++mto)
#pragma unroll
    for (int g = 0; g < 4; ++g)
#pragma unroll
      for (int j = 0; j < 2; ++j) {
        int r = g * 4 + j * 2;
        int d = j * 2 + 8 * g + 4 * hi + 32 * mto;
        u32 pk = pack2(accO[mto][r], accO[mto][r + 1]);
        *(u32*)&pO[(size_t)(half * 128 + q) * 72 + d] = pk;
      }
  if (hi == 0) ml[half * 128 + q] = l_run;
  __syncthreads();
  {
    int qq = tid >> 2, d0 = (tid & 3) * 16;   // 512 thr x 16 cols = 128x64
    float invL = 1.f / (ml[qq] + ml[128 + qq]);
    u16x8 ra0 = *(u16x8*)&pO[(size_t)qq * 72 + d0];
    u16x8 ra1 = *(u16x8*)&pO[(size_t)qq * 72 + d0 + 8];
    u16x8 rb0 = *(u16x8*)&pO[(size_t)(128 + qq) * 72 + d0];
    u16x8 rb1 = *(u16x8*)&pO[(size_t)(128 + qq) * 72 + d0 + 8];
    u16x8 o0, o1;
#pragma unroll
    for (int j = 0; j < 8; ++j) {
      o0[j] = f2bf((bf2f(ra0[j]) + bf2f(rb0[j])) * invL);
      o1[j] = f2bf((bf2f(ra1[j]) + bf2f(rb1[j])) * invL);
    }
    size_t ob = (size_t)(bx * 128 + qq) * 1024 + (size_t)h * 64 + d0;
    *(u16x8*)(attout + ob) = o0;
    *(u16x8*)(attout + ob + 8) = o1;
  }
}

// ---------------- 7. LayerNorm in-place on d_out ----------------------------
__global__ __launch_bounds__(256) void ln_kernel(float* __restrict__ io,
                                                 const float* __restrict__ gamma,
                                                 const float* __restrict__ beta) {
  int row = blockIdx.x, t = threadIdx.x;
  float4 v = *(const float4*)(io + (size_t)row * 1024 + t * 4);
  float s = v.x + v.y + v.z + v.w;
  float sq = v.x * v.x + v.y * v.y + v.z * v.z + v.w * v.w;
#pragma unroll
  for (int off = 1; off < 64; off <<= 1) {
    s += __shfl_xor(s, off, 64);
    sq += __shfl_xor(sq, off, 64);
  }
  __shared__ float rs[4], rq[4];
  if ((t & 63) == 0) { rs[t >> 6] = s; rq[t >> 6] = sq; }
  __syncthreads();
  float S = rs[0] + rs[1] + rs[2] + rs[3];
  float Q = rq[0] + rq[1] + rq[2] + rq[3];
  float mu = S * (1.f / 1024.f);
  float var = Q * (1.f / 1024.f) - mu * mu;
  float invs = rsqrtf(var + 1e-12f);
  float4 g = *(const float4*)(gamma + t * 4);
  float4 b = *(const float4*)(beta + t * 4);
  float4 o;
  o.x = (v.x - mu) * invs * g.x + b.x;
  o.y = (v.y - mu) * invs * g.y + b.y;
  o.z = (v.z - mu) * invs * g.z + b.z;
  o.w = (v.w - mu) * invs * g.w + b.w;
  *(float4*)(io + (size_t)row * 1024 + t * 4) = o;
}

extern "C" void kernel_launch(void* const* d_in, const int* in_sizes, int n_in,
                              void* d_out, int out_size, void* d_ws, size_t ws_size,
                              hipStream_t stream) {
  (void)in_sizes; (void)n_in; (void)out_size; (void)ws_size;
  const float* queries = (const float*)d_in[0];
  const float* keys    = (const float*)d_in[1];
  const float* values  = (const float*)d_in[2];
  const float* Wq = (const float*)d_in[3];
  const float* bq = (const float*)d_in[4];
  const float* Wk = (const float*)d_in[5];
  const float* bk = (const float*)d_in[6];
  const float* Wv = (const float*)d_in[7];
  const float* bv = (const float*)d_in[8];
  const float* Wo = (const float*)d_in[9];
  const float* bo = (const float*)d_in[10];
  const float* gamma = (const float*)d_in[11];
  const float* beta  = (const float*)d_in[12];
  float* out = (float*)d_out;

  u16* ws = (u16*)d_ws;
  u16* xq     = ws;                 // 12288x1024 stacked q,k,v
  u16* attout = ws;                 // 4096x1024 (after xq dead)
  u16* vt     = ws + 4194304;       // [16][64][4096] (after xk dead)
  u16* wcatT  = ws + 12582912;      // 3x 1024x1024
  u16* woT    = ws + 15728640;      // 1024x1024
  u16* qp     = ws + 16777216;      // q,k,v projections contiguous
  u16* kp     = qp + 4194304;
  u16* vp     = qp + 8388608;

  prep_kernel<<<dim3(16, 16, 5), dim3(256), 0, stream>>>(queries, keys, values, xq,
                                                         Wq, Wk, Wv, Wo, wcatT, woT);
  gemm_bt<<<dim3(8, 96), dim3(256), 0, stream>>>(xq, wcatT, qp, bq, bk, bv);
  vtrans_kernel<<<dim3(64, 16), dim3(256), 0, stream>>>(vp, vt);
  attn_kernel<<<dim3(32, 16), dim3(512), 0, stream>>>(qp, kp, vt, attout);
  gemm_n64<<<dim3(8, 64), dim3(256), 0, stream>>>(attout, woT, out, bo, queries);
  ln_kernel<<<dim3(4096), dim3(256), 0, stream>>>(out, gamma, beta);
}

// Round 10
// 179.380 us; speedup vs baseline: 2.0168x; 2.0168x over previous
//
#include <hip/hip_runtime.h>
#include <stdint.h>

typedef unsigned short u16;
typedef unsigned int u32;
typedef __attribute__((ext_vector_type(8))) __bf16 bf16x8;
typedef __attribute__((ext_vector_type(2))) __bf16 bf16x2;
typedef __attribute__((ext_vector_type(4))) float f32x4;
typedef __attribute__((ext_vector_type(16))) float f32x16;
typedef __attribute__((ext_vector_type(4))) u16 u16x4;
typedef __attribute__((ext_vector_type(8))) u16 u16x8;
typedef __attribute__((ext_vector_type(4))) u32 u32x4;

#define Q_SCALE 0.1803368801111204f  /* 0.125 / ln(2): QK^T lands in log2 domain */

__device__ __forceinline__ float ex2(float x) { return __builtin_amdgcn_exp2f(x); }

__device__ __forceinline__ u16 f2bf(float f) {
  __bf16 h = (__bf16)f;
  return __builtin_bit_cast(u16, h);
}
__device__ __forceinline__ float bf2f(u16 u) {
  u32 x = ((u32)u) << 16;
  return __builtin_bit_cast(float, x);
}
__device__ __forceinline__ u32 pack2(float a, float b) {
  bf16x2 v; v.x = (__bf16)a; v.y = (__bf16)b;
  return __builtin_bit_cast(u32, v);
}
__device__ __forceinline__ void gl_lds16(const void* g, void* l) {
  __builtin_amdgcn_global_load_lds((const __attribute__((address_space(1))) void*)g,
                                   (__attribute__((address_space(3))) void*)l, 16, 0, 0);
}

// ------- 1+2 fused. z<4: weight transpose W[k][n]->WT[n][k] bf16; z==4: cvt
__global__ __launch_bounds__(256) void prep_kernel(const float* __restrict__ q,
                                                   const float* __restrict__ k,
                                                   const float* __restrict__ v,
                                                   u16* __restrict__ xdst,
                                                   const float* __restrict__ Wq,
                                                   const float* __restrict__ Wk,
                                                   const float* __restrict__ Wv,
                                                   const float* __restrict__ Wo,
                                                   u16* __restrict__ wcatT,
                                                   u16* __restrict__ woT) {
  __shared__ u16 tile[64][72];
  int z = blockIdx.z;
  int t = threadIdx.x;
  if (z == 4) {  // fp32 -> bf16 convert for q,k,v (3 * 4194304 elems)
    int b = blockIdx.y * 16 + blockIdx.x;  // 0..255
#pragma unroll 4
    for (int it = 0; it < 24; ++it) {
      size_t tt = (size_t)b * 6144 + it * 256 + t;
      size_t e = tt * 8;
      int which = (int)(e >> 22);
      const float* s = which == 0 ? q : which == 1 ? k : v;
      size_t off = e & 4194303;
      float4 a = *(const float4*)(s + off);
      float4 bb = *(const float4*)(s + off + 4);
      u16x8 o;
      o[0] = f2bf(a.x); o[1] = f2bf(a.y); o[2] = f2bf(a.z); o[3] = f2bf(a.w);
      o[4] = f2bf(bb.x); o[5] = f2bf(bb.y); o[6] = f2bf(bb.z); o[7] = f2bf(bb.w);
      *(u16x8*)(xdst + e) = o;
    }
    return;
  }
  const float* W = z == 0 ? Wq : z == 1 ? Wk : z == 2 ? Wv : Wo;
  int k0 = blockIdx.y * 64, n0 = blockIdx.x * 64;
  int r = t >> 2, c0 = (t & 3) * 16;
  const float* src = W + (size_t)(k0 + r) * 1024 + n0 + c0;
#pragma unroll
  for (int i = 0; i < 16; i += 4) {
    float4 x = *(const float4*)(src + i);
    tile[r][c0 + i] = f2bf(x.x); tile[r][c0 + i + 1] = f2bf(x.y);
    tile[r][c0 + i + 2] = f2bf(x.z); tile[r][c0 + i + 3] = f2bf(x.w);
  }
  __syncthreads();
  int n = t >> 2, kc = (t & 3) * 16;
  u16x8 o0, o1;
#pragma unroll
  for (int j = 0; j < 8; ++j) { o0[j] = tile[kc + j][n]; o1[j] = tile[kc + 8 + j][n]; }
  u16* dst = (z < 3) ? (wcatT + (size_t)z * 1048576 + (size_t)(n0 + n) * 1024 + k0 + kc)
                     : (woT + (size_t)(n0 + n) * 1024 + k0 + kc);
  *(u16x8*)dst = o0;
  *(u16x8*)(dst + 8) = o1;
}

// ---------------- 3. GEMM mode0: QKV proj, 128x128 tile, BK=32 --------------
// sec (0=Q,1=K,2=V) is block-uniform. Q/K write row-major bf16 (+bias,
// Q*Q_SCALE). V writes V^T DIRECTLY: vt[(col)*4096 + orow], 4 consecutive
// rr rows = one aligned 8B store (vtrans kernel eliminated).
__global__ __launch_bounds__(256) void gemm_bt(const u16* __restrict__ A,
                                               const u16* __restrict__ BT,
                                               u16* __restrict__ outBF,
                                               u16* __restrict__ vt,
                                               const float* __restrict__ b0,
                                               const float* __restrict__ b1,
                                               const float* __restrict__ b2) {
  __shared__ u16 As[2][4096];
  __shared__ u16 Bs[2][4096];
  int tid = threadIdx.x;
  int bid = blockIdx.y * 8 + blockIdx.x;
  int cpx = gridDim.y;
  int swz = (bid & 7) * cpx + (bid >> 3);
  int m0 = (swz >> 3) * 128, n0 = (swz & 7) * 128;
  const u16* bt = BT + (size_t)(m0 >> 12) * 1048576;
  int w = tid >> 6, l = tid & 63;
  int wr = w >> 1, wc = w & 1;
  f32x4 acc[4][4];
#pragma unroll
  for (int i = 0; i < 4; ++i)
#pragma unroll
    for (int j = 0; j < 4; ++j)
#pragma unroll
      for (int rr = 0; rr < 4; ++rr) acc[i][j][rr] = 0.f;

  auto stage = [&](int buf, int kt) {
#pragma unroll
    for (int i = 0; i < 2; ++i) {
      int id = i * 256 + tid;
      int r = id >> 2, cp = id & 3;
      int cl = cp ^ ((r ^ (r >> 2)) & 3);
      gl_lds16(A + (size_t)(m0 + r) * 1024 + kt * 32 + cl * 8, &As[buf][id * 8]);
      gl_lds16(bt + (size_t)(n0 + r) * 1024 + kt * 32 + cl * 8, &Bs[buf][id * 8]);
    }
  };
  stage(0, 0);
  __syncthreads();
  int sw = (l & 3) ^ ((l >> 2) & 3);
  int phys = (l >> 4) ^ sw;
  for (int kt = 0; kt < 32; ++kt) {
    int buf = kt & 1;
    if (kt < 31) stage(buf ^ 1, kt + 1);
    bf16x8 af[4], bfr[4];
#pragma unroll
    for (int mi = 0; mi < 4; ++mi) {
      int row = wr * 64 + mi * 16 + (l & 15);
      af[mi] = *(const bf16x8*)&As[buf][row * 32 + phys * 8];
    }
#pragma unroll
    for (int nj = 0; nj < 4; ++nj) {
      int rowb = wc * 64 + nj * 16 + (l & 15);
      bfr[nj] = *(const bf16x8*)&Bs[buf][rowb * 32 + phys * 8];
    }
#pragma unroll
    for (int mi = 0; mi < 4; ++mi)
#pragma unroll
      for (int nj = 0; nj < 4; ++nj)
        acc[mi][nj] = __builtin_amdgcn_mfma_f32_16x16x32_bf16(af[mi], bfr[nj],
                                                              acc[mi][nj], 0, 0, 0);
    __syncthreads();
  }
  int sec = m0 >> 12;  // block-uniform
  if (sec < 2) {
    const float* bp = sec == 0 ? b0 : b1;
#pragma unroll
    for (int mi = 0; mi < 4; ++mi)
#pragma unroll
      for (int nj = 0; nj < 4; ++nj)
#pragma unroll
        for (int rr = 0; rr < 4; ++rr) {
          int row = m0 + wr * 64 + mi * 16 + (l >> 4) * 4 + rr;
          int col = n0 + wc * 64 + nj * 16 + (l & 15);
          float vv = acc[mi][nj][rr] + bp[col];
          if (sec == 0) vv *= Q_SCALE;   // fold 1/(8*ln2) into Q (exp2 softmax)
          int orow = row & 4095;
          outBF[(size_t)sec * 4194304 + (size_t)orow * 1024 + col] = f2bf(vv);
        }
  } else {
#pragma unroll
    for (int mi = 0; mi < 4; ++mi)
#pragma unroll
      for (int nj = 0; nj < 4; ++nj) {
        int col = n0 + wc * 64 + nj * 16 + (l & 15);
        float bias = b2[col];
        int orow = (m0 & 4095) + wr * 64 + mi * 16 + (l >> 4) * 4;
        u16x4 o4;
#pragma unroll
        for (int rr = 0; rr < 4; ++rr) o4[rr] = f2bf(acc[mi][nj][rr] + bias);
        *(u16x4*)(vt + (size_t)col * 4096 + orow) = o4;
      }
  }
}

// ---------------- 6. GEMM mode1: O-proj, 128x64 tile (512 blocks, 2/CU) ----
__global__ __launch_bounds__(256) void gemm_n64(const u16* __restrict__ A,
                                                const u16* __restrict__ BT,
                                                float* __restrict__ outF,
                                                const float* __restrict__ b0,
                                                const float* __restrict__ resid) {
  __shared__ u16 As[2][4096];
  __shared__ u16 Bs[2][2048];
  int tid = threadIdx.x;
  int bid = blockIdx.y * 8 + blockIdx.x;   // grid (8,64) = 512
  int swz = (bid & 7) * 64 + (bid >> 3);   // XCD chunk of 64
  int m0 = (swz >> 4) * 128, n0 = (swz & 15) * 64;
  int w = tid >> 6, l = tid & 63;
  int wr = w >> 1, wc = w & 1;
  f32x4 acc[4][2];
#pragma unroll
  for (int i = 0; i < 4; ++i)
#pragma unroll
    for (int j = 0; j < 2; ++j)
#pragma unroll
      for (int rr = 0; rr < 4; ++rr) acc[i][j][rr] = 0.f;

  auto stage = [&](int buf, int kt) {
#pragma unroll
    for (int i = 0; i < 2; ++i) {
      int id = i * 256 + tid;
      int r = id >> 2, cp = id & 3;
      int cl = cp ^ ((r ^ (r >> 2)) & 3);
      gl_lds16(A + (size_t)(m0 + r) * 1024 + kt * 32 + cl * 8, &As[buf][id * 8]);
    }
    {
      int id = tid;
      int r = id >> 2, cp = id & 3;
      int cl = cp ^ ((r ^ (r >> 2)) & 3);
      gl_lds16(BT + (size_t)(n0 + r) * 1024 + kt * 32 + cl * 8, &Bs[buf][id * 8]);
    }
  };
  stage(0, 0);
  __syncthreads();
  int sw = (l & 3) ^ ((l >> 2) & 3);
  int phys = (l >> 4) ^ sw;
  for (int kt = 0; kt < 32; ++kt) {
    int buf = kt & 1;
    if (kt < 31) stage(buf ^ 1, kt + 1);
    bf16x8 af[4], bfr[2];
#pragma unroll
    for (int mi = 0; mi < 4; ++mi) {
      int row = wr * 64 + mi * 16 + (l & 15);
      af[mi] = *(const bf16x8*)&As[buf][row * 32 + phys * 8];
    }
#pragma unroll
    for (int nj = 0; nj < 2; ++nj) {
      int rowb = wc * 32 + nj * 16 + (l & 15);
      bfr[nj] = *(const bf16x8*)&Bs[buf][rowb * 32 + phys * 8];
    }
#pragma unroll
    for (int mi = 0; mi < 4; ++mi)
#pragma unroll
      for (int nj = 0; nj < 2; ++nj)
        acc[mi][nj] = __builtin_amdgcn_mfma_f32_16x16x32_bf16(af[mi], bfr[nj],
                                                              acc[mi][nj], 0, 0, 0);
    __syncthreads();
  }
#pragma unroll
  for (int mi = 0; mi < 4; ++mi)
#pragma unroll
    for (int nj = 0; nj < 2; ++nj)
#pragma unroll
      for (int rr = 0; rr < 4; ++rr) {
        int row = m0 + wr * 64 + mi * 16 + (l >> 4) * 4 + rr;
        int col = n0 + wc * 32 + nj * 16 + (l & 15);
        outF[(size_t)row * 1024 + col] =
            acc[mi][nj][rr] + b0[col] + resid[(size_t)row * 1024 + col];
      }
}

// ---------------- 5. flash attention, intra-block KV split (R7 proven) -----
// 8 waves = 512 thr, 128 q rows; waves 0-3 stream KV[0,2048), waves 4-7
// KV[2048,4096), own dbuf LDS each. Max-free exp2 softmax; l-sum on VALU;
// P^T B-frags via v_permlane32_swap_b32 (T12); conflict-free LDS swizzle
// g(r) = (r ^ (r>>3)) & 7.
__global__ __launch_bounds__(512, 4) void attn_kernel(const u16* __restrict__ qp,
                                                      const u16* __restrict__ kp,
                                                      const u16* __restrict__ vt,
                                                      u16* __restrict__ attout) {
  __shared__ u16 smem[32768];  // 64KB: [half][buf][K 4KB | VT 4KB]
  int tid = threadIdx.x;
  int w = tid >> 6, l = tid & 63;
  int half = w >> 2, wl = w & 3;
  int hi = l >> 5, l31 = l & 31;
  int h = blockIdx.y, bx = blockIdx.x;
  int qrow = bx * 128 + wl * 32 + l31;
  bf16x8 qf[4];
#pragma unroll
  for (int ds = 0; ds < 4; ++ds)
    qf[ds] = *(const bf16x8*)(qp + (size_t)qrow * 1024 + h * 64 + ds * 16 + hi * 8);

  f32x16 zero16;
#pragma unroll
  for (int r = 0; r < 16; ++r) zero16[r] = 0.f;
  f32x16 accO[2];
#pragma unroll
  for (int r = 0; r < 16; ++r) { accO[0][r] = 0.f; accO[1][r] = 0.f; }
  float l_run = 0.f;

  u16* sbase = smem + half * 16384;
  int ht = (wl << 6) | l;  // half-local thread id, 0..255
  const u16* srcK[2]; const u16* srcV[2]; int dstOff[2];
#pragma unroll
  for (int i = 0; i < 2; ++i) {
    int id = i * 256 + ht;
    int r = id >> 3, cp = id & 7;
    int cl = cp ^ ((r ^ (r >> 3)) & 7);  // inverse swizzle on source (rule #21)
    srcK[i] = kp + (size_t)(half * 2048 + r) * 1024 + h * 64 + cl * 8;
    srcV[i] = vt + (size_t)(h * 64 + r) * 4096 + half * 2048 + cl * 8;
    dstOff[i] = id * 8;
  }
  auto stage = [&](int buf, int kt) {
    u16* b = sbase + buf * 8192;
#pragma unroll
    for (int i = 0; i < 2; ++i) {
      gl_lds16(srcK[i] + (size_t)kt * 65536, b + dstOff[i]);
      gl_lds16(srcV[i] + kt * 64, b + 4096 + dstOff[i]);
    }
  };
  stage(0, 0);
  __syncthreads();

  for (int kt = 0; kt < 32; ++kt) {
    int buf = kt & 1;
    if (kt < 31) stage(buf ^ 1, kt + 1);
    const u16* Kt = sbase + buf * 8192;
    const u16* Vt = Kt + 4096;

    // S^T = K @ Q^T (rows kv, cols q), log2 domain (Q pre-scaled)
    f32x16 accS[2];
    __builtin_amdgcn_s_setprio(1);
#pragma unroll
    for (int mt = 0; mt < 2; ++mt) {
      int row = mt * 32 + l31;
      int g = (row ^ (row >> 3)) & 7;
      {
        bf16x8 kf = *(const bf16x8*)(Kt + row * 64 + ((0 + hi) ^ g) * 8);
        accS[mt] = __builtin_amdgcn_mfma_f32_32x32x16_bf16(kf, qf[0], zero16, 0, 0, 0);
      }
#pragma unroll
      for (int ds = 1; ds < 4; ++ds) {
        int phys = (2 * ds + hi) ^ g;
        bf16x8 kf = *(const bf16x8*)(Kt + row * 64 + phys * 8);
        accS[mt] = __builtin_amdgcn_mfma_f32_32x32x16_bf16(kf, qf[ds], accS[mt], 0, 0, 0);
      }
    }
    __builtin_amdgcn_s_setprio(0);

    // p = exp2(s) directly; accumulate l partials on VALU while packing
    u32 pku[2][8];
    float s0 = 0.f, s1 = 0.f, s2 = 0.f, s3 = 0.f;
#pragma unroll
    for (int mt = 0; mt < 2; ++mt)
#pragma unroll
      for (int qd = 0; qd < 8; ++qd) {
        float a = ex2(accS[mt][2 * qd]);
        float b = ex2(accS[mt][2 * qd + 1]);
        if (qd & 1) { s2 += a; s3 += b; } else { s0 += a; s1 += b; }
        pku[mt][qd] = pack2(a, b);
      }
    float t1 = (s0 + s1) + (s2 + s3);
    t1 += __shfl_xor(t1, 32, 64);
    l_run += t1;

    // assemble P^T B-frags via permlane32_swap (A_hi <-> B_lo):
    bf16x8 pb[4];
#pragma unroll
    for (int ks = 0; ks < 4; ++ks) {
      const int mt = ks >> 1, k1 = ks & 1;
      u32 a0 = pku[mt][4 * k1 + 0], c0 = pku[mt][4 * k1 + 2];
      u32 a1 = pku[mt][4 * k1 + 1], c1 = pku[mt][4 * k1 + 3];
      asm("v_permlane32_swap_b32 %0, %1" : "+v"(a0), "+v"(c0));
      asm("v_permlane32_swap_b32 %0, %1" : "+v"(a1), "+v"(c1));
      u32x4 fr;
      fr[0] = a0; fr[1] = a1; fr[2] = c0; fr[3] = c1;
      pb[ks] = __builtin_bit_cast(bf16x8, fr);
    }
    // O^T += V^T @ P^T
    __builtin_amdgcn_s_setprio(1);
#pragma unroll
    for (int mto = 0; mto < 2; ++mto) {
      int row = mto * 32 + l31;
      int g = (row ^ (row >> 3)) & 7;
#pragma unroll
      for (int ks = 0; ks < 4; ++ks) {
        int phys = (2 * ks + hi) ^ g;
        bf16x8 vf = *(const bf16x8*)(Vt + row * 64 + phys * 8);
        accO[mto] = __builtin_amdgcn_mfma_f32_32x32x16_bf16(vf, pb[ks], accO[mto], 0, 0, 0);
      }
    }
    __builtin_amdgcn_s_setprio(0);
    __syncthreads();
  }

  // -------- cross-half combine: O = (O_A + O_B) / (l_A + l_B) --------
  u16* pO = smem;
  float* ml = (float*)(smem + 2 * 128 * 72);
  int q = wl * 32 + l31;
#pragma unroll
  for (int mto = 0; mto < 2; ++mto)
#pragma unroll
    for (int g = 0; g < 4; ++g)
#pragma unroll
      for (int j = 0; j < 2; ++j) {
        int r = g * 4 + j * 2;
        int d = j * 2 + 8 * g + 4 * hi + 32 * mto;
        u32 pk = pack2(accO[mto][r], accO[mto][r + 1]);
        *(u32*)&pO[(size_t)(half * 128 + q) * 72 + d] = pk;
      }
  if (hi == 0) ml[half * 128 + q] = l_run;
  __syncthreads();
  {
    int qq = tid >> 2, d0 = (tid & 3) * 16;   // 512 thr x 16 cols = 128x64
    float invL = 1.f / (ml[qq] + ml[128 + qq]);
    u16x8 ra0 = *(u16x8*)&pO[(size_t)qq * 72 + d0];
    u16x8 ra1 = *(u16x8*)&pO[(size_t)qq * 72 + d0 + 8];
    u16x8 rb0 = *(u16x8*)&pO[(size_t)(128 + qq) * 72 + d0];
    u16x8 rb1 = *(u16x8*)&pO[(size_t)(128 + qq) * 72 + d0 + 8];
    u16x8 o0, o1;
#pragma unroll
    for (int j = 0; j < 8; ++j) {
      o0[j] = f2bf((bf2f(ra0[j]) + bf2f(rb0[j])) * invL);
      o1[j] = f2bf((bf2f(ra1[j]) + bf2f(rb1[j])) * invL);
    }
    size_t ob = (size_t)(bx * 128 + qq) * 1024 + (size_t)h * 64 + d0;
    *(u16x8*)(attout + ob) = o0;
    *(u16x8*)(attout + ob + 8) = o1;
  }
}

// ---------------- 7. LayerNorm in-place on d_out ----------------------------
__global__ __launch_bounds__(256) void ln_kernel(float* __restrict__ io,
                                                 const float* __restrict__ gamma,
                                                 const float* __restrict__ beta) {
  int row = blockIdx.x, t = threadIdx.x;
  float4 v = *(const float4*)(io + (size_t)row * 1024 + t * 4);
  float s = v.x + v.y + v.z + v.w;
  float sq = v.x * v.x + v.y * v.y + v.z * v.z + v.w * v.w;
#pragma unroll
  for (int off = 1; off < 64; off <<= 1) {
    s += __shfl_xor(s, off, 64);
    sq += __shfl_xor(sq, off, 64);
  }
  __shared__ float rs[4], rq[4];
  if ((t & 63) == 0) { rs[t >> 6] = s; rq[t >> 6] = sq; }
  __syncthreads();
  float S = rs[0] + rs[1] + rs[2] + rs[3];
  float Q = rq[0] + rq[1] + rq[2] + rq[3];
  float mu = S * (1.f / 1024.f);
  float var = Q * (1.f / 1024.f) - mu * mu;
  float invs = rsqrtf(var + 1e-12f);
  float4 g = *(const float4*)(gamma + t * 4);
  float4 b = *(const float4*)(beta + t * 4);
  float4 o;
  o.x = (v.x - mu) * invs * g.x + b.x;
  o.y = (v.y - mu) * invs * g.y + b.y;
  o.z = (v.z - mu) * invs * g.z + b.z;
  o.w = (v.w - mu) * invs * g.w + b.w;
  *(float4*)(io + (size_t)row * 1024 + t * 4) = o;
}

extern "C" void kernel_launch(void* const* d_in, const int* in_sizes, int n_in,
                              void* d_out, int out_size, void* d_ws, size_t ws_size,
                              hipStream_t stream) {
  (void)in_sizes; (void)n_in; (void)out_size; (void)ws_size;
  const float* queries = (const float*)d_in[0];
  const float* keys    = (const float*)d_in[1];
  const float* values  = (const float*)d_in[2];
  const float* Wq = (const float*)d_in[3];
  const float* bq = (const float*)d_in[4];
  const float* Wk = (const float*)d_in[5];
  const float* bk = (const float*)d_in[6];
  const float* Wv = (const float*)d_in[7];
  const float* bv = (const float*)d_in[8];
  const float* Wo = (const float*)d_in[9];
  const float* bo = (const float*)d_in[10];
  const float* gamma = (const float*)d_in[11];
  const float* beta  = (const float*)d_in[12];
  float* out = (float*)d_out;

  u16* ws = (u16*)d_ws;
  u16* xq     = ws;                 // 12288x1024 stacked q,k,v
  u16* attout = ws;                 // 4096x1024 (after xq dead)
  u16* vt     = ws + 4194304;       // [16][64][4096] (after xk dead)
  u16* wcatT  = ws + 12582912;      // 3x 1024x1024
  u16* woT    = ws + 15728640;      // 1024x1024
  u16* qp     = ws + 16777216;      // q,k projections (V goes straight to vt)
  u16* kp     = qp + 4194304;

  prep_kernel<<<dim3(16, 16, 5), dim3(256), 0, stream>>>(queries, keys, values, xq,
                                                         Wq, Wk, Wv, Wo, wcatT, woT);
  gemm_bt<<<dim3(8, 96), dim3(256), 0, stream>>>(xq, wcatT, qp, vt, bq, bk, bv);
  attn_kernel<<<dim3(32, 16), dim3(512), 0, stream>>>(qp, kp, vt, attout);
  gemm_n64<<<dim3(8, 64), dim3(256), 0, stream>>>(attout, woT, out, bo, queries);
  ln_kernel<<<dim3(4096), dim3(256), 0, stream>>>(out, gamma, beta);
}

// Round 11
// 177.655 us; speedup vs baseline: 2.0364x; 1.0097x over previous
//
#include <hip/hip_runtime.h>
#include <stdint.h>

typedef unsigned short u16;
typedef unsigned int u32;
typedef __attribute__((ext_vector_type(8))) __bf16 bf16x8;
typedef __attribute__((ext_vector_type(2))) __bf16 bf16x2;
typedef __attribute__((ext_vector_type(4))) float f32x4;
typedef __attribute__((ext_vector_type(16))) float f32x16;
typedef __attribute__((ext_vector_type(8))) u16 u16x8;
typedef __attribute__((ext_vector_type(4))) u32 u32x4;

#define Q_SCALE 0.1803368801111204f  /* 0.125 / ln(2): QK^T lands in log2 domain */

__device__ __forceinline__ float ex2(float x) { return __builtin_amdgcn_exp2f(x); }

__device__ __forceinline__ u16 f2bf(float f) {
  __bf16 h = (__bf16)f;
  return __builtin_bit_cast(u16, h);
}
__device__ __forceinline__ float bf2f(u16 u) {
  u32 x = ((u32)u) << 16;
  return __builtin_bit_cast(float, x);
}
__device__ __forceinline__ u32 pack2(float a, float b) {
  bf16x2 v; v.x = (__bf16)a; v.y = (__bf16)b;
  return __builtin_bit_cast(u32, v);
}
__device__ __forceinline__ void gl_lds16(const void* g, void* l) {
  __builtin_amdgcn_global_load_lds((const __attribute__((address_space(1))) void*)g,
                                   (__attribute__((address_space(3))) void*)l, 16, 0, 0);
}

// ------- 1+2 fused. z<4: weight transpose W[k][n]->WT[n][k] bf16; z==4: cvt
__global__ __launch_bounds__(256) void prep_kernel(const float* __restrict__ q,
                                                   const float* __restrict__ k,
                                                   const float* __restrict__ v,
                                                   u16* __restrict__ xdst,
                                                   const float* __restrict__ Wq,
                                                   const float* __restrict__ Wk,
                                                   const float* __restrict__ Wv,
                                                   const float* __restrict__ Wo,
                                                   u16* __restrict__ wcatT,
                                                   u16* __restrict__ woT) {
  __shared__ u16 tile[64][72];
  int z = blockIdx.z;
  int t = threadIdx.x;
  if (z == 4) {  // fp32 -> bf16 convert for q,k,v (3 * 4194304 elems)
    int b = blockIdx.y * 16 + blockIdx.x;  // 0..255
#pragma unroll 4
    for (int it = 0; it < 24; ++it) {
      size_t tt = (size_t)b * 6144 + it * 256 + t;
      size_t e = tt * 8;
      int which = (int)(e >> 22);
      const float* s = which == 0 ? q : which == 1 ? k : v;
      size_t off = e & 4194303;
      float4 a = *(const float4*)(s + off);
      float4 bb = *(const float4*)(s + off + 4);
      u16x8 o;
      o[0] = f2bf(a.x); o[1] = f2bf(a.y); o[2] = f2bf(a.z); o[3] = f2bf(a.w);
      o[4] = f2bf(bb.x); o[5] = f2bf(bb.y); o[6] = f2bf(bb.z); o[7] = f2bf(bb.w);
      *(u16x8*)(xdst + e) = o;
    }
    return;
  }
  const float* W = z == 0 ? Wq : z == 1 ? Wk : z == 2 ? Wv : Wo;
  int k0 = blockIdx.y * 64, n0 = blockIdx.x * 64;
  int r = t >> 2, c0 = (t & 3) * 16;
  const float* src = W + (size_t)(k0 + r) * 1024 + n0 + c0;
#pragma unroll
  for (int i = 0; i < 16; i += 4) {
    float4 x = *(const float4*)(src + i);
    tile[r][c0 + i] = f2bf(x.x); tile[r][c0 + i + 1] = f2bf(x.y);
    tile[r][c0 + i + 2] = f2bf(x.z); tile[r][c0 + i + 3] = f2bf(x.w);
  }
  __syncthreads();
  int n = t >> 2, kc = (t & 3) * 16;
  u16x8 o0, o1;
#pragma unroll
  for (int j = 0; j < 8; ++j) { o0[j] = tile[kc + j][n]; o1[j] = tile[kc + 8 + j][n]; }
  u16* dst = (z < 3) ? (wcatT + (size_t)z * 1048576 + (size_t)(n0 + n) * 1024 + k0 + kc)
                     : (woT + (size_t)(n0 + n) * 1024 + k0 + kc);
  *(u16x8*)dst = o0;
  *(u16x8*)(dst + 8) = o1;
}

// ---------------- 3. GEMM mode0: QKV proj, 128x128 tile, BK=32 --------------
__global__ __launch_bounds__(256) void gemm_bt(const u16* __restrict__ A,
                                               const u16* __restrict__ BT,
                                               u16* __restrict__ outBF,
                                               const float* __restrict__ b0,
                                               const float* __restrict__ b1,
                                               const float* __restrict__ b2) {
  __shared__ u16 As[2][4096];
  __shared__ u16 Bs[2][4096];
  int tid = threadIdx.x;
  int bid = blockIdx.y * 8 + blockIdx.x;
  int cpx = gridDim.y;
  int swz = (bid & 7) * cpx + (bid >> 3);
  int m0 = (swz >> 3) * 128, n0 = (swz & 7) * 128;
  const u16* bt = BT + (size_t)(m0 >> 12) * 1048576;
  int w = tid >> 6, l = tid & 63;
  int wr = w >> 1, wc = w & 1;
  f32x4 acc[4][4];
#pragma unroll
  for (int i = 0; i < 4; ++i)
#pragma unroll
    for (int j = 0; j < 4; ++j)
#pragma unroll
      for (int rr = 0; rr < 4; ++rr) acc[i][j][rr] = 0.f;

  auto stage = [&](int buf, int kt) {
#pragma unroll
    for (int i = 0; i < 2; ++i) {
      int id = i * 256 + tid;
      int r = id >> 2, cp = id & 3;
      int cl = cp ^ ((r ^ (r >> 2)) & 3);
      gl_lds16(A + (size_t)(m0 + r) * 1024 + kt * 32 + cl * 8, &As[buf][id * 8]);
      gl_lds16(bt + (size_t)(n0 + r) * 1024 + kt * 32 + cl * 8, &Bs[buf][id * 8]);
    }
  };
  stage(0, 0);
  __syncthreads();
  int sw = (l & 3) ^ ((l >> 2) & 3);
  int phys = (l >> 4) ^ sw;
  for (int kt = 0; kt < 32; ++kt) {
    int buf = kt & 1;
    if (kt < 31) stage(buf ^ 1, kt + 1);
    bf16x8 af[4], bfr[4];
#pragma unroll
    for (int mi = 0; mi < 4; ++mi) {
      int row = wr * 64 + mi * 16 + (l & 15);
      af[mi] = *(const bf16x8*)&As[buf][row * 32 + phys * 8];
    }
#pragma unroll
    for (int nj = 0; nj < 4; ++nj) {
      int rowb = wc * 64 + nj * 16 + (l & 15);
      bfr[nj] = *(const bf16x8*)&Bs[buf][rowb * 32 + phys * 8];
    }
#pragma unroll
    for (int mi = 0; mi < 4; ++mi)
#pragma unroll
      for (int nj = 0; nj < 4; ++nj)
        acc[mi][nj] = __builtin_amdgcn_mfma_f32_16x16x32_bf16(af[mi], bfr[nj],
                                                              acc[mi][nj], 0, 0, 0);
    __syncthreads();
  }
#pragma unroll
  for (int mi = 0; mi < 4; ++mi)
#pragma unroll
    for (int nj = 0; nj < 4; ++nj)
#pragma unroll
      for (int rr = 0; rr < 4; ++rr) {
        int row = m0 + wr * 64 + mi * 16 + (l >> 4) * 4 + rr;
        int col = n0 + wc * 64 + nj * 16 + (l & 15);
        float vv = acc[mi][nj][rr];
        int sec = row >> 12, orow = row & 4095;
        const float* bp = sec == 0 ? b0 : sec == 1 ? b1 : b2;
        vv += bp[col];
        if (sec == 0) vv *= Q_SCALE;   // fold 1/(8*ln2) into Q (exp2 softmax)
        outBF[(size_t)sec * 4194304 + (size_t)orow * 1024 + col] = f2bf(vv);
      }
}

// ---------------- 6. GEMM mode1: O-proj, 128x64 tile (512 blocks, 2/CU) ----
__global__ __launch_bounds__(256) void gemm_n64(const u16* __restrict__ A,
                                                const u16* __restrict__ BT,
                                                float* __restrict__ outF,
                                                const float* __restrict__ b0,
                                                const float* __restrict__ resid) {
  __shared__ u16 As[2][4096];
  __shared__ u16 Bs[2][2048];
  int tid = threadIdx.x;
  int bid = blockIdx.y * 8 + blockIdx.x;   // grid (8,64) = 512
  int swz = (bid & 7) * 64 + (bid >> 3);   // XCD chunk of 64
  int m0 = (swz >> 4) * 128, n0 = (swz & 15) * 64;
  int w = tid >> 6, l = tid & 63;
  int wr = w >> 1, wc = w & 1;
  f32x4 acc[4][2];
#pragma unroll
  for (int i = 0; i < 4; ++i)
#pragma unroll
    for (int j = 0; j < 2; ++j)
#pragma unroll
      for (int rr = 0; rr < 4; ++rr) acc[i][j][rr] = 0.f;

  auto stage = [&](int buf, int kt) {
#pragma unroll
    for (int i = 0; i < 2; ++i) {
      int id = i * 256 + tid;
      int r = id >> 2, cp = id & 3;
      int cl = cp ^ ((r ^ (r >> 2)) & 3);
      gl_lds16(A + (size_t)(m0 + r) * 1024 + kt * 32 + cl * 8, &As[buf][id * 8]);
    }
    {
      int id = tid;
      int r = id >> 2, cp = id & 3;
      int cl = cp ^ ((r ^ (r >> 2)) & 3);
      gl_lds16(BT + (size_t)(n0 + r) * 1024 + kt * 32 + cl * 8, &Bs[buf][id * 8]);
    }
  };
  stage(0, 0);
  __syncthreads();
  int sw = (l & 3) ^ ((l >> 2) & 3);
  int phys = (l >> 4) ^ sw;
  for (int kt = 0; kt < 32; ++kt) {
    int buf = kt & 1;
    if (kt < 31) stage(buf ^ 1, kt + 1);
    bf16x8 af[4], bfr[2];
#pragma unroll
    for (int mi = 0; mi < 4; ++mi) {
      int row = wr * 64 + mi * 16 + (l & 15);
      af[mi] = *(const bf16x8*)&As[buf][row * 32 + phys * 8];
    }
#pragma unroll
    for (int nj = 0; nj < 2; ++nj) {
      int rowb = wc * 32 + nj * 16 + (l & 15);
      bfr[nj] = *(const bf16x8*)&Bs[buf][rowb * 32 + phys * 8];
    }
#pragma unroll
    for (int mi = 0; mi < 4; ++mi)
#pragma unroll
      for (int nj = 0; nj < 2; ++nj)
        acc[mi][nj] = __builtin_amdgcn_mfma_f32_16x16x32_bf16(af[mi], bfr[nj],
                                                              acc[mi][nj], 0, 0, 0);
    __syncthreads();
  }
#pragma unroll
  for (int mi = 0; mi < 4; ++mi)
#pragma unroll
    for (int nj = 0; nj < 2; ++nj)
#pragma unroll
      for (int rr = 0; rr < 4; ++rr) {
        int row = m0 + wr * 64 + mi * 16 + (l >> 4) * 4 + rr;
        int col = n0 + wc * 32 + nj * 16 + (l & 15);
        outF[(size_t)row * 1024 + col] =
            acc[mi][nj][rr] + b0[col] + resid[(size_t)row * 1024 + col];
      }
}

// ---------------- 4. V transpose per head: vp[n][h*64+d] -> vt[h][d][n] ----
__global__ __launch_bounds__(256) void vtrans_kernel(const u16* __restrict__ vp,
                                                     u16* __restrict__ vt) {
  __shared__ u16 tile[64][72];
  int t = threadIdx.x;
  int n0 = blockIdx.x * 64, h = blockIdx.y;
  int r = t >> 2, c0 = (t & 3) * 16;
  u16x8 a = *(const u16x8*)(vp + (size_t)(n0 + r) * 1024 + h * 64 + c0);
  u16x8 b = *(const u16x8*)(vp + (size_t)(n0 + r) * 1024 + h * 64 + c0 + 8);
#pragma unroll
  for (int j = 0; j < 8; ++j) { tile[r][c0 + j] = a[j]; tile[r][c0 + 8 + j] = b[j]; }
  __syncthreads();
  int d = t >> 2, nc = (t & 3) * 16;
  u16x8 o0, o1;
#pragma unroll
  for (int j = 0; j < 8; ++j) { o0[j] = tile[nc + j][d]; o1[j] = tile[nc + 8 + j][d]; }
  size_t base = (size_t)(h * 64 + d) * 4096 + n0 + nc;
  *(u16x8*)(vt + base) = o0;
  *(u16x8*)(vt + base + 8) = o1;
}

// ---------------- 5. flash attention, KVBLK=32, target 4 blocks/CU ----------
// R9's structure (proven correct) with __launch_bounds__(512,4): LDS 38KB ->
// 4 blocks/CU if VGPR<=64 (natural; R7/R10 measured exactly 64). R9's (512,8)
// forced VGPR=32 -> spill storm; this retries the occupancy theory cleanly.
__global__ __launch_bounds__(512, 4) void attn_kernel(const u16* __restrict__ qp,
                                                      const u16* __restrict__ kp,
                                                      const u16* __restrict__ vt,
                                                      u16* __restrict__ attout) {
  __shared__ u16 smem[19456];  // 38KB; loop uses [0,16384): [half][buf][K 2K|V 2K]
  int tid = threadIdx.x;
  int w = tid >> 6, l = tid & 63;
  int half = w >> 2, wl = w & 3;
  int hi = l >> 5, l31 = l & 31;
  int h = blockIdx.y, bx = blockIdx.x;
  int qrow = bx * 128 + wl * 32 + l31;
  bf16x8 qf[4];
#pragma unroll
  for (int ds = 0; ds < 4; ++ds)
    qf[ds] = *(const bf16x8*)(qp + (size_t)qrow * 1024 + h * 64 + ds * 16 + hi * 8);

  f32x16 accO[2];
#pragma unroll
  for (int r = 0; r < 16; ++r) { accO[0][r] = 0.f; accO[1][r] = 0.f; }
  float l_run = 0.f;

  u16* sbase = smem + half * 8192;
  int ht = (wl << 6) | l;  // half-local thread id, 0..255
  // stage sources, inverse-swizzled (rule #21)
  int rK = ht >> 3, cpK = ht & 7;
  int clK = cpK ^ ((rK ^ (rK >> 3)) & 7);
  const u16* srcK = kp + (size_t)(half * 2048 + rK) * 1024 + h * 64 + clK * 8;
  int dV = ht >> 2, cpV = ht & 3;
  int clV = cpV ^ (((dV >> 1) ^ (dV >> 3)) & 3);
  const u16* srcV = vt + (size_t)(h * 64 + dV) * 4096 + half * 2048 + clV * 8;
  int dstK = ht * 8, dstV = 2048 + ht * 8;
  auto stage = [&](int buf, int kt) {
    u16* b = sbase + buf * 4096;
    gl_lds16(srcK + (size_t)kt * 32768, b + dstK);
    gl_lds16(srcV + kt * 32, b + dstV);
  };
  stage(0, 0);
  __syncthreads();

  int gK = (l31 ^ (l31 >> 3)) & 7;
  int gV = ((l31 >> 1) ^ (l31 >> 3)) & 3;  // same value for row 32+l31

  for (int kt = 0; kt < 64; ++kt) {
    int buf = kt & 1;
    if (kt < 63) stage(buf ^ 1, kt + 1);
    const u16* Kt = sbase + buf * 4096;
    const u16* Vt = Kt + 2048;

    // S^T = K @ Q^T (32 kv x 32 q), log2 domain (Q pre-scaled)
    f32x16 accS;
#pragma unroll
    for (int r = 0; r < 16; ++r) accS[r] = 0.f;
    __builtin_amdgcn_s_setprio(1);
#pragma unroll
    for (int ds = 0; ds < 4; ++ds) {
      bf16x8 kf = *(const bf16x8*)(Kt + l31 * 64 + ((2 * ds + hi) ^ gK) * 8);
      accS = __builtin_amdgcn_mfma_f32_32x32x16_bf16(kf, qf[ds], accS, 0, 0, 0);
    }
    __builtin_amdgcn_s_setprio(0);

    // p = exp2(s) directly; accumulate l partials on VALU while packing
    u32 pku[8];
    float s0 = 0.f, s1 = 0.f, s2 = 0.f, s3 = 0.f;
#pragma unroll
    for (int qd = 0; qd < 8; ++qd) {
      float a = ex2(accS[2 * qd]);
      float b = ex2(accS[2 * qd + 1]);
      if (qd & 1) { s2 += a; s3 += b; } else { s0 += a; s1 += b; }
      pku[qd] = pack2(a, b);
    }
    float t1 = (s0 + s1) + (s2 + s3);
    t1 += __shfl_xor(t1, 32, 64);
    l_run += t1;

    // assemble P^T B-frags via permlane32_swap (A_hi <-> B_lo)
    bf16x8 pb0, pb1;
    {
      u32 a0 = pku[0], c0 = pku[2], a1 = pku[1], c1 = pku[3];
      asm("v_permlane32_swap_b32 %0, %1" : "+v"(a0), "+v"(c0));
      asm("v_permlane32_swap_b32 %0, %1" : "+v"(a1), "+v"(c1));
      u32x4 fr; fr[0] = a0; fr[1] = a1; fr[2] = c0; fr[3] = c1;
      pb0 = __builtin_bit_cast(bf16x8, fr);
      u32 a2 = pku[4], c2 = pku[6], a3 = pku[5], c3 = pku[7];
      asm("v_permlane32_swap_b32 %0, %1" : "+v"(a2), "+v"(c2));
      asm("v_permlane32_swap_b32 %0, %1" : "+v"(a3), "+v"(c3));
      u32x4 fr2; fr2[0] = a2; fr2[1] = a3; fr2[2] = c2; fr2[3] = c3;
      pb1 = __builtin_bit_cast(bf16x8, fr2);
    }
    // O^T += V^T @ P^T
    __builtin_amdgcn_s_setprio(1);
    {
      bf16x8 vf;
      vf = *(const bf16x8*)(Vt + l31 * 32 + ((0 + hi) ^ gV) * 8);
      accO[0] = __builtin_amdgcn_mfma_f32_32x32x16_bf16(vf, pb0, accO[0], 0, 0, 0);
      vf = *(const bf16x8*)(Vt + l31 * 32 + ((2 + hi) ^ gV) * 8);
      accO[0] = __builtin_amdgcn_mfma_f32_32x32x16_bf16(vf, pb1, accO[0], 0, 0, 0);
      vf = *(const bf16x8*)(Vt + (32 + l31) * 32 + ((0 + hi) ^ gV) * 8);
      accO[1] = __builtin_amdgcn_mfma_f32_32x32x16_bf16(vf, pb0, accO[1], 0, 0, 0);
      vf = *(const bf16x8*)(Vt + (32 + l31) * 32 + ((2 + hi) ^ gV) * 8);
      accO[1] = __builtin_amdgcn_mfma_f32_32x32x16_bf16(vf, pb1, accO[1], 0, 0, 0);
    }
    __builtin_amdgcn_s_setprio(0);
    __syncthreads();
  }

  // -------- cross-half combine: O = (O_A + O_B) / (l_A + l_B) --------
  // pO[half][q 128][72 u16] (bf16, unnormalized), ml[half][q 128] f32
  u16* pO = smem;
  float* ml = (float*)(smem + 18432);
  int q = wl * 32 + l31;
#pragma unroll
  for (int mto = 0; mto < 2; ++mto)
#pragma unroll
    for (int g = 0; g < 4; ++g)
#pragma unroll
      for (int j = 0; j < 2; ++j) {
        int r = g * 4 + j * 2;
        int d = j * 2 + 8 * g + 4 * hi + 32 * mto;
        u32 pk = pack2(accO[mto][r], accO[mto][r + 1]);
        *(u32*)&pO[(size_t)(half * 128 + q) * 72 + d] = pk;
      }
  if (hi == 0) ml[half * 128 + q] = l_run;
  __syncthreads();
  {
    int qq = tid >> 2, d0 = (tid & 3) * 16;   // 512 thr x 16 cols = 128x64
    float invL = 1.f / (ml[qq] + ml[128 + qq]);
    u16x8 ra0 = *(u16x8*)&pO[(size_t)qq * 72 + d0];
    u16x8 ra1 = *(u16x8*)&pO[(size_t)qq * 72 + d0 + 8];
    u16x8 rb0 = *(u16x8*)&pO[(size_t)(128 + qq) * 72 + d0];
    u16x8 rb1 = *(u16x8*)&pO[(size_t)(128 + qq) * 72 + d0 + 8];
    u16x8 o0, o1;
#pragma unroll
    for (int j = 0; j < 8; ++j) {
      o0[j] = f2bf((bf2f(ra0[j]) + bf2f(rb0[j])) * invL);
      o1[j] = f2bf((bf2f(ra1[j]) + bf2f(rb1[j])) * invL);
    }
    size_t ob = (size_t)(bx * 128 + qq) * 1024 + (size_t)h * 64 + d0;
    *(u16x8*)(attout + ob) = o0;
    *(u16x8*)(attout + ob + 8) = o1;
  }
}

// ---------------- 7. LayerNorm in-place on d_out ----------------------------
__global__ __launch_bounds__(256) void ln_kernel(float* __restrict__ io,
                                                 const float* __restrict__ gamma,
                                                 const float* __restrict__ beta) {
  int row = blockIdx.x, t = threadIdx.x;
  float4 v = *(const float4*)(io + (size_t)row * 1024 + t * 4);
  float s = v.x + v.y + v.z + v.w;
  float sq = v.x * v.x + v.y * v.y + v.z * v.z + v.w * v.w;
#pragma unroll
  for (int off = 1; off < 64; off <<= 1) {
    s += __shfl_xor(s, off, 64);
    sq += __shfl_xor(sq, off, 64);
  }
  __shared__ float rs[4], rq[4];
  if ((t & 63) == 0) { rs[t >> 6] = s; rq[t >> 6] = sq; }
  __syncthreads();
  float S = rs[0] + rs[1] + rs[2] + rs[3];
  float Q = rq[0] + rq[1] + rq[2] + rq[3];
  float mu = S * (1.f / 1024.f);
  float var = Q * (1.f / 1024.f) - mu * mu;
  float invs = rsqrtf(var + 1e-12f);
  float4 g = *(const float4*)(gamma + t * 4);
  float4 b = *(const float4*)(beta + t * 4);
  float4 o;
  o.x = (v.x - mu) * invs * g.x + b.x;
  o.y = (v.y - mu) * invs * g.y + b.y;
  o.z = (v.z - mu) * invs * g.z + b.z;
  o.w = (v.w - mu) * invs * g.w + b.w;
  *(float4*)(io + (size_t)row * 1024 + t * 4) = o;
}

extern "C" void kernel_launch(void* const* d_in, const int* in_sizes, int n_in,
                              void* d_out, int out_size, void* d_ws, size_t ws_size,
                              hipStream_t stream) {
  (void)in_sizes; (void)n_in; (void)out_size; (void)ws_size;
  const float* queries = (const float*)d_in[0];
  const float* keys    = (const float*)d_in[1];
  const float* values  = (const float*)d_in[2];
  const float* Wq = (const float*)d_in[3];
  const float* bq = (const float*)d_in[4];
  const float* Wk = (const float*)d_in[5];
  const float* bk = (const float*)d_in[6];
  const float* Wv = (const float*)d_in[7];
  const float* bv = (const float*)d_in[8];
  const float* Wo = (const float*)d_in[9];
  const float* bo = (const float*)d_in[10];
  const float* gamma = (const float*)d_in[11];
  const float* beta  = (const float*)d_in[12];
  float* out = (float*)d_out;

  u16* ws = (u16*)d_ws;
  u16* xq     = ws;                 // 12288x1024 stacked q,k,v
  u16* attout = ws;                 // 4096x1024 (after xq dead)
  u16* vt     = ws + 4194304;       // [16][64][4096] (after xk dead)
  u16* wcatT  = ws + 12582912;      // 3x 1024x1024
  u16* woT    = ws + 15728640;      // 1024x1024
  u16* qp     = ws + 16777216;      // q,k,v projections contiguous
  u16* kp     = qp + 4194304;
  u16* vp     = qp + 8388608;

  prep_kernel<<<dim3(16, 16, 5), dim3(256), 0, stream>>>(queries, keys, values, xq,
                                                         Wq, Wk, Wv, Wo, wcatT, woT);
  gemm_bt<<<dim3(8, 96), dim3(256), 0, stream>>>(xq, wcatT, qp, bq, bk, bv);
  vtrans_kernel<<<dim3(64, 16), dim3(256), 0, stream>>>(vp, vt);
  attn_kernel<<<dim3(32, 16), dim3(512), 0, stream>>>(qp, kp, vt, attout);
  gemm_n64<<<dim3(8, 64), dim3(256), 0, stream>>>(attout, woT, out, bo, queries);
  ln_kernel<<<dim3(4096), dim3(256), 0, stream>>>(out, gamma, beta);
}

// Round 12
// 175.777 us; speedup vs baseline: 2.0582x; 1.0107x over previous
//
#include <hip/hip_runtime.h>
#include <stdint.h>

typedef unsigned short u16;
typedef unsigned int u32;
typedef __attribute__((ext_vector_type(8))) __bf16 bf16x8;
typedef __attribute__((ext_vector_type(2))) __bf16 bf16x2;
typedef __attribute__((ext_vector_type(4))) float f32x4;
typedef __attribute__((ext_vector_type(16))) float f32x16;
typedef __attribute__((ext_vector_type(8))) u16 u16x8;
typedef __attribute__((ext_vector_type(4))) u32 u32x4;

#define Q_SCALE 0.1803368801111204f  /* 0.125 / ln(2): QK^T lands in log2 domain */

__device__ __forceinline__ float ex2(float x) { return __builtin_amdgcn_exp2f(x); }

__device__ __forceinline__ u16 f2bf(float f) {
  __bf16 h = (__bf16)f;
  return __builtin_bit_cast(u16, h);
}
__device__ __forceinline__ float bf2f(u16 u) {
  u32 x = ((u32)u) << 16;
  return __builtin_bit_cast(float, x);
}
__device__ __forceinline__ u32 pack2(float a, float b) {
  bf16x2 v; v.x = (__bf16)a; v.y = (__bf16)b;
  return __builtin_bit_cast(u32, v);
}
__device__ __forceinline__ void gl_lds16(const void* g, void* l) {
  __builtin_amdgcn_global_load_lds((const __attribute__((address_space(1))) void*)g,
                                   (__attribute__((address_space(3))) void*)l, 16, 0, 0);
}

// ------- 1+2 fused. z<4: weight transpose W[k][n]->WT[n][k] bf16; z==4: cvt
__global__ __launch_bounds__(256) void prep_kernel(const float* __restrict__ q,
                                                   const float* __restrict__ k,
                                                   const float* __restrict__ v,
                                                   u16* __restrict__ xdst,
                                                   const float* __restrict__ Wq,
                                                   const float* __restrict__ Wk,
                                                   const float* __restrict__ Wv,
                                                   const float* __restrict__ Wo,
                                                   u16* __restrict__ wcatT,
                                                   u16* __restrict__ woT) {
  __shared__ u16 tile[64][72];
  int z = blockIdx.z;
  int t = threadIdx.x;
  if (z == 4) {  // fp32 -> bf16 convert for q,k,v (3 * 4194304 elems)
    int b = blockIdx.y * 16 + blockIdx.x;  // 0..255
#pragma unroll 4
    for (int it = 0; it < 24; ++it) {
      size_t tt = (size_t)b * 6144 + it * 256 + t;
      size_t e = tt * 8;
      int which = (int)(e >> 22);
      const float* s = which == 0 ? q : which == 1 ? k : v;
      size_t off = e & 4194303;
      float4 a = *(const float4*)(s + off);
      float4 bb = *(const float4*)(s + off + 4);
      u16x8 o;
      o[0] = f2bf(a.x); o[1] = f2bf(a.y); o[2] = f2bf(a.z); o[3] = f2bf(a.w);
      o[4] = f2bf(bb.x); o[5] = f2bf(bb.y); o[6] = f2bf(bb.z); o[7] = f2bf(bb.w);
      *(u16x8*)(xdst + e) = o;
    }
    return;
  }
  const float* W = z == 0 ? Wq : z == 1 ? Wk : z == 2 ? Wv : Wo;
  int k0 = blockIdx.y * 64, n0 = blockIdx.x * 64;
  int r = t >> 2, c0 = (t & 3) * 16;
  const float* src = W + (size_t)(k0 + r) * 1024 + n0 + c0;
#pragma unroll
  for (int i = 0; i < 16; i += 4) {
    float4 x = *(const float4*)(src + i);
    tile[r][c0 + i] = f2bf(x.x); tile[r][c0 + i + 1] = f2bf(x.y);
    tile[r][c0 + i + 2] = f2bf(x.z); tile[r][c0 + i + 3] = f2bf(x.w);
  }
  __syncthreads();
  int n = t >> 2, kc = (t & 3) * 16;
  u16x8 o0, o1;
#pragma unroll
  for (int j = 0; j < 8; ++j) { o0[j] = tile[kc + j][n]; o1[j] = tile[kc + 8 + j][n]; }
  u16* dst = (z < 3) ? (wcatT + (size_t)z * 1048576 + (size_t)(n0 + n) * 1024 + k0 + kc)
                     : (woT + (size_t)(n0 + n) * 1024 + k0 + kc);
  *(u16x8*)dst = o0;
  *(u16x8*)(dst + 8) = o1;
}

// ---------------- 3. GEMM mode0: QKV proj, 128x128 tile, BK=32 --------------
__global__ __launch_bounds__(256) void gemm_bt(const u16* __restrict__ A,
                                               const u16* __restrict__ BT,
                                               u16* __restrict__ outBF,
                                               const float* __restrict__ b0,
                                               const float* __restrict__ b1,
                                               const float* __restrict__ b2) {
  __shared__ u16 As[2][4096];
  __shared__ u16 Bs[2][4096];
  int tid = threadIdx.x;
  int bid = blockIdx.y * 8 + blockIdx.x;
  int cpx = gridDim.y;
  int swz = (bid & 7) * cpx + (bid >> 3);
  int m0 = (swz >> 3) * 128, n0 = (swz & 7) * 128;
  const u16* bt = BT + (size_t)(m0 >> 12) * 1048576;
  int w = tid >> 6, l = tid & 63;
  int wr = w >> 1, wc = w & 1;
  f32x4 acc[4][4];
#pragma unroll
  for (int i = 0; i < 4; ++i)
#pragma unroll
    for (int j = 0; j < 4; ++j)
#pragma unroll
      for (int rr = 0; rr < 4; ++rr) acc[i][j][rr] = 0.f;

  auto stage = [&](int buf, int kt) {
#pragma unroll
    for (int i = 0; i < 2; ++i) {
      int id = i * 256 + tid;
      int r = id >> 2, cp = id & 3;
      int cl = cp ^ ((r ^ (r >> 2)) & 3);
      gl_lds16(A + (size_t)(m0 + r) * 1024 + kt * 32 + cl * 8, &As[buf][id * 8]);
      gl_lds16(bt + (size_t)(n0 + r) * 1024 + kt * 32 + cl * 8, &Bs[buf][id * 8]);
    }
  };
  stage(0, 0);
  __syncthreads();
  int sw = (l & 3) ^ ((l >> 2) & 3);
  int phys = (l >> 4) ^ sw;
  for (int kt = 0; kt < 32; ++kt) {
    int buf = kt & 1;
    if (kt < 31) stage(buf ^ 1, kt + 1);
    bf16x8 af[4], bfr[4];
#pragma unroll
    for (int mi = 0; mi < 4; ++mi) {
      int row = wr * 64 + mi * 16 + (l & 15);
      af[mi] = *(const bf16x8*)&As[buf][row * 32 + phys * 8];
    }
#pragma unroll
    for (int nj = 0; nj < 4; ++nj) {
      int rowb = wc * 64 + nj * 16 + (l & 15);
      bfr[nj] = *(const bf16x8*)&Bs[buf][rowb * 32 + phys * 8];
    }
#pragma unroll
    for (int mi = 0; mi < 4; ++mi)
#pragma unroll
      for (int nj = 0; nj < 4; ++nj)
        acc[mi][nj] = __builtin_amdgcn_mfma_f32_16x16x32_bf16(af[mi], bfr[nj],
                                                              acc[mi][nj], 0, 0, 0);
    __syncthreads();
  }
#pragma unroll
  for (int mi = 0; mi < 4; ++mi)
#pragma unroll
    for (int nj = 0; nj < 4; ++nj)
#pragma unroll
      for (int rr = 0; rr < 4; ++rr) {
        int row = m0 + wr * 64 + mi * 16 + (l >> 4) * 4 + rr;
        int col = n0 + wc * 64 + nj * 16 + (l & 15);
        float vv = acc[mi][nj][rr];
        int sec = row >> 12, orow = row & 4095;
        const float* bp = sec == 0 ? b0 : sec == 1 ? b1 : b2;
        vv += bp[col];
        if (sec == 0) vv *= Q_SCALE;   // fold 1/(8*ln2) into Q (exp2 softmax)
        outBF[(size_t)sec * 4194304 + (size_t)orow * 1024 + col] = f2bf(vv);
      }
}

// ---------------- 6. GEMM mode1: O-proj, 128x64 tile (512 blocks, 2/CU) ----
__global__ __launch_bounds__(256) void gemm_n64(const u16* __restrict__ A,
                                                const u16* __restrict__ BT,
                                                float* __restrict__ outF,
                                                const float* __restrict__ b0,
                                                const float* __restrict__ resid) {
  __shared__ u16 As[2][4096];
  __shared__ u16 Bs[2][2048];
  int tid = threadIdx.x;
  int bid = blockIdx.y * 8 + blockIdx.x;   // grid (8,64) = 512
  int swz = (bid & 7) * 64 + (bid >> 3);   // XCD chunk of 64
  int m0 = (swz >> 4) * 128, n0 = (swz & 15) * 64;
  int w = tid >> 6, l = tid & 63;
  int wr = w >> 1, wc = w & 1;
  f32x4 acc[4][2];
#pragma unroll
  for (int i = 0; i < 4; ++i)
#pragma unroll
    for (int j = 0; j < 2; ++j)
#pragma unroll
      for (int rr = 0; rr < 4; ++rr) acc[i][j][rr] = 0.f;

  auto stage = [&](int buf, int kt) {
#pragma unroll
    for (int i = 0; i < 2; ++i) {
      int id = i * 256 + tid;
      int r = id >> 2, cp = id & 3;
      int cl = cp ^ ((r ^ (r >> 2)) & 3);
      gl_lds16(A + (size_t)(m0 + r) * 1024 + kt * 32 + cl * 8, &As[buf][id * 8]);
    }
    {
      int id = tid;
      int r = id >> 2, cp = id & 3;
      int cl = cp ^ ((r ^ (r >> 2)) & 3);
      gl_lds16(BT + (size_t)(n0 + r) * 1024 + kt * 32 + cl * 8, &Bs[buf][id * 8]);
    }
  };
  stage(0, 0);
  __syncthreads();
  int sw = (l & 3) ^ ((l >> 2) & 3);
  int phys = (l >> 4) ^ sw;
  for (int kt = 0; kt < 32; ++kt) {
    int buf = kt & 1;
    if (kt < 31) stage(buf ^ 1, kt + 1);
    bf16x8 af[4], bfr[2];
#pragma unroll
    for (int mi = 0; mi < 4; ++mi) {
      int row = wr * 64 + mi * 16 + (l & 15);
      af[mi] = *(const bf16x8*)&As[buf][row * 32 + phys * 8];
    }
#pragma unroll
    for (int nj = 0; nj < 2; ++nj) {
      int rowb = wc * 32 + nj * 16 + (l & 15);
      bfr[nj] = *(const bf16x8*)&Bs[buf][rowb * 32 + phys * 8];
    }
#pragma unroll
    for (int mi = 0; mi < 4; ++mi)
#pragma unroll
      for (int nj = 0; nj < 2; ++nj)
        acc[mi][nj] = __builtin_amdgcn_mfma_f32_16x16x32_bf16(af[mi], bfr[nj],
                                                              acc[mi][nj], 0, 0, 0);
    __syncthreads();
  }
#pragma unroll
  for (int mi = 0; mi < 4; ++mi)
#pragma unroll
    for (int nj = 0; nj < 2; ++nj)
#pragma unroll
      for (int rr = 0; rr < 4; ++rr) {
        int row = m0 + wr * 64 + mi * 16 + (l >> 4) * 4 + rr;
        int col = n0 + wc * 32 + nj * 16 + (l & 15);
        outF[(size_t)row * 1024 + col] =
            acc[mi][nj][rr] + b0[col] + resid[(size_t)row * 1024 + col];
      }
}

// ---------------- 4. V transpose per head: vp[n][h*64+d] -> vt[h][d][n] ----
__global__ __launch_bounds__(256) void vtrans_kernel(const u16* __restrict__ vp,
                                                     u16* __restrict__ vt) {
  __shared__ u16 tile[64][72];
  int t = threadIdx.x;
  int n0 = blockIdx.x * 64, h = blockIdx.y;
  int r = t >> 2, c0 = (t & 3) * 16;
  u16x8 a = *(const u16x8*)(vp + (size_t)(n0 + r) * 1024 + h * 64 + c0);
  u16x8 b = *(const u16x8*)(vp + (size_t)(n0 + r) * 1024 + h * 64 + c0 + 8);
#pragma unroll
  for (int j = 0; j < 8; ++j) { tile[r][c0 + j] = a[j]; tile[r][c0 + 8 + j] = b[j]; }
  __syncthreads();
  int d = t >> 2, nc = (t & 3) * 16;
  u16x8 o0, o1;
#pragma unroll
  for (int j = 0; j < 8; ++j) { o0[j] = tile[nc + j][d]; o1[j] = tile[nc + 8 + j][d]; }
  size_t base = (size_t)(h * 64 + d) * 4096 + n0 + nc;
  *(u16x8*)(vt + base) = o0;
  *(u16x8*)(vt + base + 8) = o1;
}

// ---------------- 5. flash attention, intra-block KV split (R7 proven) -----
// 8 waves = 512 thr, 128 q rows; waves 0-3 stream KV[0,2048), waves 4-7
// KV[2048,4096), own dbuf LDS each. Max-free exp2 softmax; l-sum on VALU
// with the cross-lane shfl DEFERRED out of the loop (linear in tiles);
// P^T B-frags via v_permlane32_swap_b32 (T12); conflict-free LDS swizzle
// g(r) = (r ^ (r>>3)) & 7.
__global__ __launch_bounds__(512, 4) void attn_kernel(const u16* __restrict__ qp,
                                                      const u16* __restrict__ kp,
                                                      const u16* __restrict__ vt,
                                                      u16* __restrict__ attout) {
  __shared__ u16 smem[32768];  // 64KB: [half][buf][K 4KB | VT 4KB]
  int tid = threadIdx.x;
  int w = tid >> 6, l = tid & 63;
  int half = w >> 2, wl = w & 3;
  int hi = l >> 5, l31 = l & 31;
  int h = blockIdx.y, bx = blockIdx.x;
  int qrow = bx * 128 + wl * 32 + l31;
  bf16x8 qf[4];
#pragma unroll
  for (int ds = 0; ds < 4; ++ds)
    qf[ds] = *(const bf16x8*)(qp + (size_t)qrow * 1024 + h * 64 + ds * 16 + hi * 8);

  f32x16 zero16;
#pragma unroll
  for (int r = 0; r < 16; ++r) zero16[r] = 0.f;
  f32x16 accO[2];
#pragma unroll
  for (int r = 0; r < 16; ++r) { accO[0][r] = 0.f; accO[1][r] = 0.f; }
  float l_run = 0.f;

  u16* sbase = smem + half * 16384;
  int ht = (wl << 6) | l;  // half-local thread id, 0..255
  const u16* srcK[2]; const u16* srcV[2]; int dstOff[2];
#pragma unroll
  for (int i = 0; i < 2; ++i) {
    int id = i * 256 + ht;
    int r = id >> 3, cp = id & 7;
    int cl = cp ^ ((r ^ (r >> 3)) & 7);  // inverse swizzle on source (rule #21)
    srcK[i] = kp + (size_t)(half * 2048 + r) * 1024 + h * 64 + cl * 8;
    srcV[i] = vt + (size_t)(h * 64 + r) * 4096 + half * 2048 + cl * 8;
    dstOff[i] = id * 8;
  }
  auto stage = [&](int buf, int kt) {
    u16* b = sbase + buf * 8192;
#pragma unroll
    for (int i = 0; i < 2; ++i) {
      gl_lds16(srcK[i] + (size_t)kt * 65536, b + dstOff[i]);
      gl_lds16(srcV[i] + kt * 64, b + 4096 + dstOff[i]);
    }
  };
  stage(0, 0);
  __syncthreads();

  for (int kt = 0; kt < 32; ++kt) {
    int buf = kt & 1;
    if (kt < 31) stage(buf ^ 1, kt + 1);
    const u16* Kt = sbase + buf * 8192;
    const u16* Vt = Kt + 4096;

    // S^T = K @ Q^T (rows kv, cols q), log2 domain (Q pre-scaled)
    f32x16 accS[2];
    __builtin_amdgcn_s_setprio(1);
#pragma unroll
    for (int mt = 0; mt < 2; ++mt) {
      int row = mt * 32 + l31;
      int g = (row ^ (row >> 3)) & 7;
      {
        bf16x8 kf = *(const bf16x8*)(Kt + row * 64 + ((0 + hi) ^ g) * 8);
        accS[mt] = __builtin_amdgcn_mfma_f32_32x32x16_bf16(kf, qf[0], zero16, 0, 0, 0);
      }
#pragma unroll
      for (int ds = 1; ds < 4; ++ds) {
        int phys = (2 * ds + hi) ^ g;
        bf16x8 kf = *(const bf16x8*)(Kt + row * 64 + phys * 8);
        accS[mt] = __builtin_amdgcn_mfma_f32_32x32x16_bf16(kf, qf[ds], accS[mt], 0, 0, 0);
      }
    }
    __builtin_amdgcn_s_setprio(0);

    // p = exp2(s) directly; accumulate l partials on VALU while packing.
    // Cross-lane shfl for l is deferred out of the loop (linear in tiles).
    u32 pku[2][8];
    float s0 = 0.f, s1 = 0.f, s2 = 0.f, s3 = 0.f;
#pragma unroll
    for (int mt = 0; mt < 2; ++mt)
#pragma unroll
      for (int qd = 0; qd < 8; ++qd) {
        float a = ex2(accS[mt][2 * qd]);
        float b = ex2(accS[mt][2 * qd + 1]);
        if (qd & 1) { s2 += a; s3 += b; } else { s0 += a; s1 += b; }
        pku[mt][qd] = pack2(a, b);
      }
    l_run += (s0 + s1) + (s2 + s3);

    // assemble P^T B-frags via permlane32_swap (A_hi <-> B_lo):
    bf16x8 pb[4];
#pragma unroll
    for (int ks = 0; ks < 4; ++ks) {
      const int mt = ks >> 1, k1 = ks & 1;
      u32 a0 = pku[mt][4 * k1 + 0], c0 = pku[mt][4 * k1 + 2];
      u32 a1 = pku[mt][4 * k1 + 1], c1 = pku[mt][4 * k1 + 3];
      asm("v_permlane32_swap_b32 %0, %1" : "+v"(a0), "+v"(c0));
      asm("v_permlane32_swap_b32 %0, %1" : "+v"(a1), "+v"(c1));
      u32x4 fr;
      fr[0] = a0; fr[1] = a1; fr[2] = c0; fr[3] = c1;
      pb[ks] = __builtin_bit_cast(bf16x8, fr);
    }
    // O^T += V^T @ P^T
    __builtin_amdgcn_s_setprio(1);
#pragma unroll
    for (int mto = 0; mto < 2; ++mto) {
      int row = mto * 32 + l31;
      int g = (row ^ (row >> 3)) & 7;
#pragma unroll
      for (int ks = 0; ks < 4; ++ks) {
        int phys = (2 * ks + hi) ^ g;
        bf16x8 vf = *(const bf16x8*)(Vt + row * 64 + phys * 8);
        accO[mto] = __builtin_amdgcn_mfma_f32_32x32x16_bf16(vf, pb[ks], accO[mto], 0, 0, 0);
      }
    }
    __builtin_amdgcn_s_setprio(0);
    __syncthreads();
  }
  l_run += __shfl_xor(l_run, 32, 64);   // deferred cross-lane l reduce

  // -------- cross-half combine: O = (O_A + O_B) / (l_A + l_B) --------
  u16* pO = smem;
  float* ml = (float*)(smem + 2 * 128 * 72);
  int q = wl * 32 + l31;
#pragma unroll
  for (int mto = 0; mto < 2; ++mto)
#pragma unroll
    for (int g = 0; g < 4; ++g)
#pragma unroll
      for (int j = 0; j < 2; ++j) {
        int r = g * 4 + j * 2;
        int d = j * 2 + 8 * g + 4 * hi + 32 * mto;
        u32 pk = pack2(accO[mto][r], accO[mto][r + 1]);
        *(u32*)&pO[(size_t)(half * 128 + q) * 72 + d] = pk;
      }
  if (hi == 0) ml[half * 128 + q] = l_run;
  __syncthreads();
  {
    int qq = tid >> 2, d0 = (tid & 3) * 16;   // 512 thr x 16 cols = 128x64
    float invL = 1.f / (ml[qq] + ml[128 + qq]);
    u16x8 ra0 = *(u16x8*)&pO[(size_t)qq * 72 + d0];
    u16x8 ra1 = *(u16x8*)&pO[(size_t)qq * 72 + d0 + 8];
    u16x8 rb0 = *(u16x8*)&pO[(size_t)(128 + qq) * 72 + d0];
    u16x8 rb1 = *(u16x8*)&pO[(size_t)(128 + qq) * 72 + d0 + 8];
    u16x8 o0, o1;
#pragma unroll
    for (int j = 0; j < 8; ++j) {
      o0[j] = f2bf((bf2f(ra0[j]) + bf2f(rb0[j])) * invL);
      o1[j] = f2bf((bf2f(ra1[j]) + bf2f(rb1[j])) * invL);
    }
    size_t ob = (size_t)(bx * 128 + qq) * 1024 + (size_t)h * 64 + d0;
    *(u16x8*)(attout + ob) = o0;
    *(u16x8*)(attout + ob + 8) = o1;
  }
}

// ---------------- 7. LayerNorm in-place on d_out ----------------------------
__global__ __launch_bounds__(256) void ln_kernel(float* __restrict__ io,
                                                 const float* __restrict__ gamma,
                                                 const float* __restrict__ beta) {
  int row = blockIdx.x, t = threadIdx.x;
  float4 v = *(const float4*)(io + (size_t)row * 1024 + t * 4);
  float s = v.x + v.y + v.z + v.w;
  float sq = v.x * v.x + v.y * v.y + v.z * v.z + v.w * v.w;
#pragma unroll
  for (int off = 1; off < 64; off <<= 1) {
    s += __shfl_xor(s, off, 64);
    sq += __shfl_xor(sq, off, 64);
  }
  __shared__ float rs[4], rq[4];
  if ((t & 63) == 0) { rs[t >> 6] = s; rq[t >> 6] = sq; }
  __syncthreads();
  float S = rs[0] + rs[1] + rs[2] + rs[3];
  float Q = rq[0] + rq[1] + rq[2] + rq[3];
  float mu = S * (1.f / 1024.f);
  float var = Q * (1.f / 1024.f) - mu * mu;
  float invs = rsqrtf(var + 1e-12f);
  float4 g = *(const float4*)(gamma + t * 4);
  float4 b = *(const float4*)(beta + t * 4);
  float4 o;
  o.x = (v.x - mu) * invs * g.x + b.x;
  o.y = (v.y - mu) * invs * g.y + b.y;
  o.z = (v.z - mu) * invs * g.z + b.z;
  o.w = (v.w - mu) * invs * g.w + b.w;
  *(float4*)(io + (size_t)row * 1024 + t * 4) = o;
}

extern "C" void kernel_launch(void* const* d_in, const int* in_sizes, int n_in,
                              void* d_out, int out_size, void* d_ws, size_t ws_size,
                              hipStream_t stream) {
  (void)in_sizes; (void)n_in; (void)out_size; (void)ws_size;
  const float* queries = (const float*)d_in[0];
  const float* keys    = (const float*)d_in[1];
  const float* values  = (const float*)d_in[2];
  const float* Wq = (const float*)d_in[3];
  const float* bq = (const float*)d_in[4];
  const float* Wk = (const float*)d_in[5];
  const float* bk = (const float*)d_in[6];
  const float* Wv = (const float*)d_in[7];
  const float* bv = (const float*)d_in[8];
  const float* Wo = (const float*)d_in[9];
  const float* bo = (const float*)d_in[10];
  const float* gamma = (const float*)d_in[11];
  const float* beta  = (const float*)d_in[12];
  float* out = (float*)d_out;

  u16* ws = (u16*)d_ws;
  u16* xq     = ws;                 // 12288x1024 stacked q,k,v
  u16* attout = ws;                 // 4096x1024 (after xq dead)
  u16* vt     = ws + 4194304;       // [16][64][4096] (after xk dead)
  u16* wcatT  = ws + 12582912;      // 3x 1024x1024
  u16* woT    = ws + 15728640;      // 1024x1024
  u16* qp     = ws + 16777216;      // q,k,v projections contiguous
  u16* kp     = qp + 4194304;
  u16* vp     = qp + 8388608;

  prep_kernel<<<dim3(16, 16, 5), dim3(256), 0, stream>>>(queries, keys, values, xq,
                                                         Wq, Wk, Wv, Wo, wcatT, woT);
  gemm_bt<<<dim3(8, 96), dim3(256), 0, stream>>>(xq, wcatT, qp, bq, bk, bv);
  vtrans_kernel<<<dim3(64, 16), dim3(256), 0, stream>>>(vp, vt);
  attn_kernel<<<dim3(32, 16), dim3(512), 0, stream>>>(qp, kp, vt, attout);
  gemm_n64<<<dim3(8, 64), dim3(256), 0, stream>>>(attout, woT, out, bo, queries);
  ln_kernel<<<dim3(4096), dim3(256), 0, stream>>>(out, gamma, beta);
}

// Round 13
// 171.051 us; speedup vs baseline: 2.1150x; 1.0276x over previous
//
#include <hip/hip_runtime.h>
#include <stdint.h>

typedef unsigned short u16;
typedef unsigned int u32;
typedef __attribute__((ext_vector_type(8))) __bf16 bf16x8;
typedef __attribute__((ext_vector_type(2))) __bf16 bf16x2;
typedef __attribute__((ext_vector_type(4))) float f32x4;
typedef __attribute__((ext_vector_type(16))) float f32x16;
typedef __attribute__((ext_vector_type(8))) u16 u16x8;
typedef __attribute__((ext_vector_type(4))) u32 u32x4;

#define Q_SCALE 0.1803368801111204f  /* 0.125 / ln(2): QK^T lands in log2 domain */

__device__ __forceinline__ float ex2(float x) { return __builtin_amdgcn_exp2f(x); }

__device__ __forceinline__ u16 f2bf(float f) {
  __bf16 h = (__bf16)f;
  return __builtin_bit_cast(u16, h);
}
__device__ __forceinline__ float bf2f(u16 u) {
  u32 x = ((u32)u) << 16;
  return __builtin_bit_cast(float, x);
}
__device__ __forceinline__ u32 pack2(float a, float b) {
  bf16x2 v; v.x = (__bf16)a; v.y = (__bf16)b;
  return __builtin_bit_cast(u32, v);
}
__device__ __forceinline__ void gl_lds16(const void* g, void* l) {
  __builtin_amdgcn_global_load_lds((const __attribute__((address_space(1))) void*)g,
                                   (__attribute__((address_space(3))) void*)l, 16, 0, 0);
}

// ------- 2. weight transpose W[k][n] -> WT[n][k] bf16 (cvt fused into GEMM)
__global__ __launch_bounds__(256) void prep_kernel(const float* __restrict__ Wq,
                                                   const float* __restrict__ Wk,
                                                   const float* __restrict__ Wv,
                                                   const float* __restrict__ Wo,
                                                   u16* __restrict__ wcatT,
                                                   u16* __restrict__ woT) {
  __shared__ u16 tile[64][72];
  int z = blockIdx.z;
  int t = threadIdx.x;
  const float* W = z == 0 ? Wq : z == 1 ? Wk : z == 2 ? Wv : Wo;
  int k0 = blockIdx.y * 64, n0 = blockIdx.x * 64;
  int r = t >> 2, c0 = (t & 3) * 16;
  const float* src = W + (size_t)(k0 + r) * 1024 + n0 + c0;
#pragma unroll
  for (int i = 0; i < 16; i += 4) {
    float4 x = *(const float4*)(src + i);
    tile[r][c0 + i] = f2bf(x.x); tile[r][c0 + i + 1] = f2bf(x.y);
    tile[r][c0 + i + 2] = f2bf(x.z); tile[r][c0 + i + 3] = f2bf(x.w);
  }
  __syncthreads();
  int n = t >> 2, kc = (t & 3) * 16;
  u16x8 o0, o1;
#pragma unroll
  for (int j = 0; j < 8; ++j) { o0[j] = tile[kc + j][n]; o1[j] = tile[kc + 8 + j][n]; }
  u16* dst = (z < 3) ? (wcatT + (size_t)z * 1048576 + (size_t)(n0 + n) * 1024 + k0 + kc)
                     : (woT + (size_t)(n0 + n) * 1024 + k0 + kc);
  *(u16x8*)dst = o0;
  *(u16x8*)(dst + 8) = o1;
}

// ---------------- 3. GEMM mode0: QKV proj, 128x128 tile, BK=32 --------------
// A is read DIRECTLY as fp32 from queries/keys/values (sec = m0>>12 is
// block-uniform), converted in-register, ds_write_b128 into the swizzled
// LDS layout (T14 split: loads issued at loop top, LDS write after MFMAs).
// The separate cvt kernel + xq buffer are eliminated (-48MB HBM traffic).
__global__ __launch_bounds__(256) void gemm_bt(const float* __restrict__ Aq,
                                               const float* __restrict__ Ak,
                                               const float* __restrict__ Av,
                                               const u16* __restrict__ BT,
                                               u16* __restrict__ outBF,
                                               const float* __restrict__ b0,
                                               const float* __restrict__ b1,
                                               const float* __restrict__ b2) {
  __shared__ u16 As[2][4096];
  __shared__ u16 Bs[2][4096];
  int tid = threadIdx.x;
  int bid = blockIdx.y * 8 + blockIdx.x;
  int cpx = gridDim.y;
  int swz = (bid & 7) * cpx + (bid >> 3);
  int m0 = (swz >> 3) * 128, n0 = (swz & 7) * 128;
  int sec = m0 >> 12;                     // block-uniform section
  const float* A32 = sec == 0 ? Aq : sec == 1 ? Ak : Av;
  int mbase = m0 & 4095;
  const u16* bt = BT + (size_t)sec * 1048576;
  int w = tid >> 6, l = tid & 63;
  int wr = w >> 1, wc = w & 1;
  f32x4 acc[4][4];
#pragma unroll
  for (int i = 0; i < 4; ++i)
#pragma unroll
    for (int j = 0; j < 4; ++j)
#pragma unroll
      for (int rr = 0; rr < 4; ++rr) acc[i][j][rr] = 0.f;

  // per-thread A stage addressing (swizzled source, rule #21)
  const float* srcA[2]; int dstA[2];
#pragma unroll
  for (int i = 0; i < 2; ++i) {
    int id = i * 256 + tid;
    int r = id >> 2, cp = id & 3;
    int cl = cp ^ ((r ^ (r >> 2)) & 3);
    srcA[i] = A32 + (size_t)(mbase + r) * 1024 + cl * 8;
    dstA[i] = id * 8;
  }
  auto loadA = [&](int kt, float4* pa, float4* pb4) {
#pragma unroll
    for (int i = 0; i < 2; ++i) {
      pa[i] = *(const float4*)(srcA[i] + kt * 32);
      pb4[i] = *(const float4*)(srcA[i] + kt * 32 + 4);
    }
  };
  auto writeA = [&](int buf, const float4* pa, const float4* pb4) {
#pragma unroll
    for (int i = 0; i < 2; ++i) {
      u16x8 o;
      o[0] = f2bf(pa[i].x); o[1] = f2bf(pa[i].y);
      o[2] = f2bf(pa[i].z); o[3] = f2bf(pa[i].w);
      o[4] = f2bf(pb4[i].x); o[5] = f2bf(pb4[i].y);
      o[6] = f2bf(pb4[i].z); o[7] = f2bf(pb4[i].w);
      *(u16x8*)&As[buf][dstA[i]] = o;
    }
  };
  auto stageB = [&](int buf, int kt) {
#pragma unroll
    for (int i = 0; i < 2; ++i) {
      int id = i * 256 + tid;
      int r = id >> 2, cp = id & 3;
      int cl = cp ^ ((r ^ (r >> 2)) & 3);
      gl_lds16(bt + (size_t)(n0 + r) * 1024 + kt * 32 + cl * 8, &Bs[buf][id * 8]);
    }
  };
  float4 pa[2], pb4[2];
  loadA(0, pa, pb4);
  stageB(0, 0);
  writeA(0, pa, pb4);
  __syncthreads();
  int sw = (l & 3) ^ ((l >> 2) & 3);
  int phys = (l >> 4) ^ sw;
  for (int kt = 0; kt < 32; ++kt) {
    int buf = kt & 1;
    if (kt < 31) {
      loadA(kt + 1, pa, pb4);
      stageB(buf ^ 1, kt + 1);
    }
    bf16x8 af[4], bfr[4];
#pragma unroll
    for (int mi = 0; mi < 4; ++mi) {
      int row = wr * 64 + mi * 16 + (l & 15);
      af[mi] = *(const bf16x8*)&As[buf][row * 32 + phys * 8];
    }
#pragma unroll
    for (int nj = 0; nj < 4; ++nj) {
      int rowb = wc * 64 + nj * 16 + (l & 15);
      bfr[nj] = *(const bf16x8*)&Bs[buf][rowb * 32 + phys * 8];
    }
#pragma unroll
    for (int mi = 0; mi < 4; ++mi)
#pragma unroll
      for (int nj = 0; nj < 4; ++nj)
        acc[mi][nj] = __builtin_amdgcn_mfma_f32_16x16x32_bf16(af[mi], bfr[nj],
                                                              acc[mi][nj], 0, 0, 0);
    if (kt < 31) writeA(buf ^ 1, pa, pb4);
    __syncthreads();
  }
  const float* bp = sec == 0 ? b0 : sec == 1 ? b1 : b2;
#pragma unroll
  for (int mi = 0; mi < 4; ++mi)
#pragma unroll
    for (int nj = 0; nj < 4; ++nj)
#pragma unroll
      for (int rr = 0; rr < 4; ++rr) {
        int orow = mbase + wr * 64 + mi * 16 + (l >> 4) * 4 + rr;
        int col = n0 + wc * 64 + nj * 16 + (l & 15);
        float vv = acc[mi][nj][rr] + bp[col];
        if (sec == 0) vv *= Q_SCALE;   // fold 1/(8*ln2) into Q (exp2 softmax)
        outBF[(size_t)sec * 4194304 + (size_t)orow * 1024 + col] = f2bf(vv);
      }
}

// ---------------- 6. GEMM mode1: O-proj, 128x64 tile (512 blocks, 2/CU) ----
__global__ __launch_bounds__(256) void gemm_n64(const u16* __restrict__ A,
                                                const u16* __restrict__ BT,
                                                float* __restrict__ outF,
                                                const float* __restrict__ b0,
                                                const float* __restrict__ resid) {
  __shared__ u16 As[2][4096];
  __shared__ u16 Bs[2][2048];
  int tid = threadIdx.x;
  int bid = blockIdx.y * 8 + blockIdx.x;   // grid (8,64) = 512
  int swz = (bid & 7) * 64 + (bid >> 3);   // XCD chunk of 64
  int m0 = (swz >> 4) * 128, n0 = (swz & 15) * 64;
  int w = tid >> 6, l = tid & 63;
  int wr = w >> 1, wc = w & 1;
  f32x4 acc[4][2];
#pragma unroll
  for (int i = 0; i < 4; ++i)
#pragma unroll
    for (int j = 0; j < 2; ++j)
#pragma unroll
      for (int rr = 0; rr < 4; ++rr) acc[i][j][rr] = 0.f;

  auto stage = [&](int buf, int kt) {
#pragma unroll
    for (int i = 0; i < 2; ++i) {
      int id = i * 256 + tid;
      int r = id >> 2, cp = id & 3;
      int cl = cp ^ ((r ^ (r >> 2)) & 3);
      gl_lds16(A + (size_t)(m0 + r) * 1024 + kt * 32 + cl * 8, &As[buf][id * 8]);
    }
    {
      int id = tid;
      int r = id >> 2, cp = id & 3;
      int cl = cp ^ ((r ^ (r >> 2)) & 3);
      gl_lds16(BT + (size_t)(n0 + r) * 1024 + kt * 32 + cl * 8, &Bs[buf][id * 8]);
    }
  };
  stage(0, 0);
  __syncthreads();
  int sw = (l & 3) ^ ((l >> 2) & 3);
  int phys = (l >> 4) ^ sw;
  for (int kt = 0; kt < 32; ++kt) {
    int buf = kt & 1;
    if (kt < 31) stage(buf ^ 1, kt + 1);
    bf16x8 af[4], bfr[2];
#pragma unroll
    for (int mi = 0; mi < 4; ++mi) {
      int row = wr * 64 + mi * 16 + (l & 15);
      af[mi] = *(const bf16x8*)&As[buf][row * 32 + phys * 8];
    }
#pragma unroll
    for (int nj = 0; nj < 2; ++nj) {
      int rowb = wc * 32 + nj * 16 + (l & 15);
      bfr[nj] = *(const bf16x8*)&Bs[buf][rowb * 32 + phys * 8];
    }
#pragma unroll
    for (int mi = 0; mi < 4; ++mi)
#pragma unroll
      for (int nj = 0; nj < 2; ++nj)
        acc[mi][nj] = __builtin_amdgcn_mfma_f32_16x16x32_bf16(af[mi], bfr[nj],
                                                              acc[mi][nj], 0, 0, 0);
    __syncthreads();
  }
#pragma unroll
  for (int mi = 0; mi < 4; ++mi)
#pragma unroll
    for (int nj = 0; nj < 2; ++nj)
#pragma unroll
      for (int rr = 0; rr < 4; ++rr) {
        int row = m0 + wr * 64 + mi * 16 + (l >> 4) * 4 + rr;
        int col = n0 + wc * 32 + nj * 16 + (l & 15);
        outF[(size_t)row * 1024 + col] =
            acc[mi][nj][rr] + b0[col] + resid[(size_t)row * 1024 + col];
      }
}

// ---------------- 4. V transpose per head: vp[n][h*64+d] -> vt[h][d][n] ----
__global__ __launch_bounds__(256) void vtrans_kernel(const u16* __restrict__ vp,
                                                     u16* __restrict__ vt) {
  __shared__ u16 tile[64][72];
  int t = threadIdx.x;
  int n0 = blockIdx.x * 64, h = blockIdx.y;
  int r = t >> 2, c0 = (t & 3) * 16;
  u16x8 a = *(const u16x8*)(vp + (size_t)(n0 + r) * 1024 + h * 64 + c0);
  u16x8 b = *(const u16x8*)(vp + (size_t)(n0 + r) * 1024 + h * 64 + c0 + 8);
#pragma unroll
  for (int j = 0; j < 8; ++j) { tile[r][c0 + j] = a[j]; tile[r][c0 + 8 + j] = b[j]; }
  __syncthreads();
  int d = t >> 2, nc = (t & 3) * 16;
  u16x8 o0, o1;
#pragma unroll
  for (int j = 0; j < 8; ++j) { o0[j] = tile[nc + j][d]; o1[j] = tile[nc + 8 + j][d]; }
  size_t base = (size_t)(h * 64 + d) * 4096 + n0 + nc;
  *(u16x8*)(vt + base) = o0;
  *(u16x8*)(vt + base + 8) = o1;
}

// ---------------- 5. flash attention, intra-block KV split (frozen) --------
__global__ __launch_bounds__(512, 4) void attn_kernel(const u16* __restrict__ qp,
                                                      const u16* __restrict__ kp,
                                                      const u16* __restrict__ vt,
                                                      u16* __restrict__ attout) {
  __shared__ u16 smem[32768];  // 64KB: [half][buf][K 4KB | VT 4KB]
  int tid = threadIdx.x;
  int w = tid >> 6, l = tid & 63;
  int half = w >> 2, wl = w & 3;
  int hi = l >> 5, l31 = l & 31;
  int h = blockIdx.y, bx = blockIdx.x;
  int qrow = bx * 128 + wl * 32 + l31;
  bf16x8 qf[4];
#pragma unroll
  for (int ds = 0; ds < 4; ++ds)
    qf[ds] = *(const bf16x8*)(qp + (size_t)qrow * 1024 + h * 64 + ds * 16 + hi * 8);

  f32x16 zero16;
#pragma unroll
  for (int r = 0; r < 16; ++r) zero16[r] = 0.f;
  f32x16 accO[2];
#pragma unroll
  for (int r = 0; r < 16; ++r) { accO[0][r] = 0.f; accO[1][r] = 0.f; }
  float l_run = 0.f;

  u16* sbase = smem + half * 16384;
  int ht = (wl << 6) | l;  // half-local thread id, 0..255
  const u16* srcK[2]; const u16* srcV[2]; int dstOff[2];
#pragma unroll
  for (int i = 0; i < 2; ++i) {
    int id = i * 256 + ht;
    int r = id >> 3, cp = id & 7;
    int cl = cp ^ ((r ^ (r >> 3)) & 7);  // inverse swizzle on source (rule #21)
    srcK[i] = kp + (size_t)(half * 2048 + r) * 1024 + h * 64 + cl * 8;
    srcV[i] = vt + (size_t)(h * 64 + r) * 4096 + half * 2048 + cl * 8;
    dstOff[i] = id * 8;
  }
  auto stage = [&](int buf, int kt) {
    u16* b = sbase + buf * 8192;
#pragma unroll
    for (int i = 0; i < 2; ++i) {
      gl_lds16(srcK[i] + (size_t)kt * 65536, b + dstOff[i]);
      gl_lds16(srcV[i] + kt * 64, b + 4096 + dstOff[i]);
    }
  };
  stage(0, 0);
  __syncthreads();

  for (int kt = 0; kt < 32; ++kt) {
    int buf = kt & 1;
    if (kt < 31) stage(buf ^ 1, kt + 1);
    const u16* Kt = sbase + buf * 8192;
    const u16* Vt = Kt + 4096;

    // S^T = K @ Q^T (rows kv, cols q), log2 domain (Q pre-scaled)
    f32x16 accS[2];
    __builtin_amdgcn_s_setprio(1);
#pragma unroll
    for (int mt = 0; mt < 2; ++mt) {
      int row = mt * 32 + l31;
      int g = (row ^ (row >> 3)) & 7;
      {
        bf16x8 kf = *(const bf16x8*)(Kt + row * 64 + ((0 + hi) ^ g) * 8);
        accS[mt] = __builtin_amdgcn_mfma_f32_32x32x16_bf16(kf, qf[0], zero16, 0, 0, 0);
      }
#pragma unroll
      for (int ds = 1; ds < 4; ++ds) {
        int phys = (2 * ds + hi) ^ g;
        bf16x8 kf = *(const bf16x8*)(Kt + row * 64 + phys * 8);
        accS[mt] = __builtin_amdgcn_mfma_f32_32x32x16_bf16(kf, qf[ds], accS[mt], 0, 0, 0);
      }
    }
    __builtin_amdgcn_s_setprio(0);

    // p = exp2(s) directly; l partials on VALU; cross-lane shfl deferred
    u32 pku[2][8];
    float s0 = 0.f, s1 = 0.f, s2 = 0.f, s3 = 0.f;
#pragma unroll
    for (int mt = 0; mt < 2; ++mt)
#pragma unroll
      for (int qd = 0; qd < 8; ++qd) {
        float a = ex2(accS[mt][2 * qd]);
        float b = ex2(accS[mt][2 * qd + 1]);
        if (qd & 1) { s2 += a; s3 += b; } else { s0 += a; s1 += b; }
        pku[mt][qd] = pack2(a, b);
      }
    l_run += (s0 + s1) + (s2 + s3);

    // assemble P^T B-frags via permlane32_swap (A_hi <-> B_lo):
    bf16x8 pb[4];
#pragma unroll
    for (int ks = 0; ks < 4; ++ks) {
      const int mt = ks >> 1, k1 = ks & 1;
      u32 a0 = pku[mt][4 * k1 + 0], c0 = pku[mt][4 * k1 + 2];
      u32 a1 = pku[mt][4 * k1 + 1], c1 = pku[mt][4 * k1 + 3];
      asm("v_permlane32_swap_b32 %0, %1" : "+v"(a0), "+v"(c0));
      asm("v_permlane32_swap_b32 %0, %1" : "+v"(a1), "+v"(c1));
      u32x4 fr;
      fr[0] = a0; fr[1] = a1; fr[2] = c0; fr[3] = c1;
      pb[ks] = __builtin_bit_cast(bf16x8, fr);
    }
    // O^T += V^T @ P^T
    __builtin_amdgcn_s_setprio(1);
#pragma unroll
    for (int mto = 0; mto < 2; ++mto) {
      int row = mto * 32 + l31;
      int g = (row ^ (row >> 3)) & 7;
#pragma unroll
      for (int ks = 0; ks < 4; ++ks) {
        int phys = (2 * ks + hi) ^ g;
        bf16x8 vf = *(const bf16x8*)(Vt + row * 64 + phys * 8);
        accO[mto] = __builtin_amdgcn_mfma_f32_32x32x16_bf16(vf, pb[ks], accO[mto], 0, 0, 0);
      }
    }
    __builtin_amdgcn_s_setprio(0);
    __syncthreads();
  }
  l_run += __shfl_xor(l_run, 32, 64);   // deferred cross-lane l reduce

  // -------- cross-half combine: O = (O_A + O_B) / (l_A + l_B) --------
  u16* pO = smem;
  float* ml = (float*)(smem + 2 * 128 * 72);
  int q = wl * 32 + l31;
#pragma unroll
  for (int mto = 0; mto < 2; ++mto)
#pragma unroll
    for (int g = 0; g < 4; ++g)
#pragma unroll
      for (int j = 0; j < 2; ++j) {
        int r = g * 4 + j * 2;
        int d = j * 2 + 8 * g + 4 * hi + 32 * mto;
        u32 pk = pack2(accO[mto][r], accO[mto][r + 1]);
        *(u32*)&pO[(size_t)(half * 128 + q) * 72 + d] = pk;
      }
  if (hi == 0) ml[half * 128 + q] = l_run;
  __syncthreads();
  {
    int qq = tid >> 2, d0 = (tid & 3) * 16;   // 512 thr x 16 cols = 128x64
    float invL = 1.f / (ml[qq] + ml[128 + qq]);
    u16x8 ra0 = *(u16x8*)&pO[(size_t)qq * 72 + d0];
    u16x8 ra1 = *(u16x8*)&pO[(size_t)qq * 72 + d0 + 8];
    u16x8 rb0 = *(u16x8*)&pO[(size_t)(128 + qq) * 72 + d0];
    u16x8 rb1 = *(u16x8*)&pO[(size_t)(128 + qq) * 72 + d0 + 8];
    u16x8 o0, o1;
#pragma unroll
    for (int j = 0; j < 8; ++j) {
      o0[j] = f2bf((bf2f(ra0[j]) + bf2f(rb0[j])) * invL);
      o1[j] = f2bf((bf2f(ra1[j]) + bf2f(rb1[j])) * invL);
    }
    size_t ob = (size_t)(bx * 128 + qq) * 1024 + (size_t)h * 64 + d0;
    *(u16x8*)(attout + ob) = o0;
    *(u16x8*)(attout + ob + 8) = o1;
  }
}

// ---------------- 7. LayerNorm in-place on d_out ----------------------------
__global__ __launch_bounds__(256) void ln_kernel(float* __restrict__ io,
                                                 const float* __restrict__ gamma,
                                                 const float* __restrict__ beta) {
  int row = blockIdx.x, t = threadIdx.x;
  float4 v = *(const float4*)(io + (size_t)row * 1024 + t * 4);
  float s = v.x + v.y + v.z + v.w;
  float sq = v.x * v.x + v.y * v.y + v.z * v.z + v.w * v.w;
#pragma unroll
  for (int off = 1; off < 64; off <<= 1) {
    s += __shfl_xor(s, off, 64);
    sq += __shfl_xor(sq, off, 64);
  }
  __shared__ float rs[4], rq[4];
  if ((t & 63) == 0) { rs[t >> 6] = s; rq[t >> 6] = sq; }
  __syncthreads();
  float S = rs[0] + rs[1] + rs[2] + rs[3];
  float Q = rq[0] + rq[1] + rq[2] + rq[3];
  float mu = S * (1.f / 1024.f);
  float var = Q * (1.f / 1024.f) - mu * mu;
  float invs = rsqrtf(var + 1e-12f);
  float4 g = *(const float4*)(gamma + t * 4);
  float4 b = *(const float4*)(beta + t * 4);
  float4 o;
  o.x = (v.x - mu) * invs * g.x + b.x;
  o.y = (v.y - mu) * invs * g.y + b.y;
  o.z = (v.z - mu) * invs * g.z + b.z;
  o.w = (v.w - mu) * invs * g.w + b.w;
  *(float4*)(io + (size_t)row * 1024 + t * 4) = o;
}

extern "C" void kernel_launch(void* const* d_in, const int* in_sizes, int n_in,
                              void* d_out, int out_size, void* d_ws, size_t ws_size,
                              hipStream_t stream) {
  (void)in_sizes; (void)n_in; (void)out_size; (void)ws_size;
  const float* queries = (const float*)d_in[0];
  const float* keys    = (const float*)d_in[1];
  const float* values  = (const float*)d_in[2];
  const float* Wq = (const float*)d_in[3];
  const float* bq = (const float*)d_in[4];
  const float* Wk = (const float*)d_in[5];
  const float* bk = (const float*)d_in[6];
  const float* Wv = (const float*)d_in[7];
  const float* bv = (const float*)d_in[8];
  const float* Wo = (const float*)d_in[9];
  const float* bo = (const float*)d_in[10];
  const float* gamma = (const float*)d_in[11];
  const float* beta  = (const float*)d_in[12];
  float* out = (float*)d_out;

  u16* ws = (u16*)d_ws;
  u16* attout = ws;                 // 4096x1024
  u16* vt     = ws + 4194304;       // [16][64][4096]
  u16* wcatT  = ws + 12582912;      // 3x 1024x1024
  u16* woT    = ws + 15728640;      // 1024x1024
  u16* qp     = ws + 16777216;      // q,k,v projections contiguous
  u16* kp     = qp + 4194304;
  u16* vp     = qp + 8388608;

  prep_kernel<<<dim3(16, 16, 4), dim3(256), 0, stream>>>(Wq, Wk, Wv, Wo, wcatT, woT);
  gemm_bt<<<dim3(8, 96), dim3(256), 0, stream>>>(queries, keys, values, wcatT, qp,
                                                 bq, bk, bv);
  vtrans_kernel<<<dim3(64, 16), dim3(256), 0, stream>>>(vp, vt);
  attn_kernel<<<dim3(32, 16), dim3(512), 0, stream>>>(qp, kp, vt, attout);
  gemm_n64<<<dim3(8, 64), dim3(256), 0, stream>>>(attout, woT, out, bo, queries);
  ln_kernel<<<dim3(4096), dim3(256), 0, stream>>>(out, gamma, beta);
}

// Round 14
// 160.234 us; speedup vs baseline: 2.2578x; 1.0675x over previous
//
#include <hip/hip_runtime.h>
#include <stdint.h>

typedef unsigned short u16;
typedef unsigned int u32;
typedef __attribute__((ext_vector_type(8))) __bf16 bf16x8;
typedef __attribute__((ext_vector_type(2))) __bf16 bf16x2;
typedef __attribute__((ext_vector_type(4))) float f32x4;
typedef __attribute__((ext_vector_type(16))) float f32x16;
typedef __attribute__((ext_vector_type(8))) u16 u16x8;
typedef __attribute__((ext_vector_type(4))) u32 u32x4;

#define Q_SCALE 0.1803368801111204f  /* 0.125 / ln(2): QK^T lands in log2 domain */

__device__ __forceinline__ float ex2(float x) { return __builtin_amdgcn_exp2f(x); }

__device__ __forceinline__ u16 f2bf(float f) {
  __bf16 h = (__bf16)f;
  return __builtin_bit_cast(u16, h);
}
__device__ __forceinline__ float bf2f(u16 u) {
  u32 x = ((u32)u) << 16;
  return __builtin_bit_cast(float, x);
}
__device__ __forceinline__ u32 pack2(float a, float b) {
  bf16x2 v; v.x = (__bf16)a; v.y = (__bf16)b;
  return __builtin_bit_cast(u32, v);
}
__device__ __forceinline__ void gl_lds16(const void* g, void* l) {
  __builtin_amdgcn_global_load_lds((const __attribute__((address_space(1))) void*)g,
                                   (__attribute__((address_space(3))) void*)l, 16, 0, 0);
}

// ------- 2. weight transpose W[k][n] -> WT[n][k] bf16 (cvt fused into GEMM)
__global__ __launch_bounds__(256) void prep_kernel(const float* __restrict__ Wq,
                                                   const float* __restrict__ Wk,
                                                   const float* __restrict__ Wv,
                                                   const float* __restrict__ Wo,
                                                   u16* __restrict__ wcatT,
                                                   u16* __restrict__ woT) {
  __shared__ u16 tile[64][72];
  int z = blockIdx.z;
  int t = threadIdx.x;
  const float* W = z == 0 ? Wq : z == 1 ? Wk : z == 2 ? Wv : Wo;
  int k0 = blockIdx.y * 64, n0 = blockIdx.x * 64;
  int r = t >> 2, c0 = (t & 3) * 16;
  const float* src = W + (size_t)(k0 + r) * 1024 + n0 + c0;
#pragma unroll
  for (int i = 0; i < 16; i += 4) {
    float4 x = *(const float4*)(src + i);
    tile[r][c0 + i] = f2bf(x.x); tile[r][c0 + i + 1] = f2bf(x.y);
    tile[r][c0 + i + 2] = f2bf(x.z); tile[r][c0 + i + 3] = f2bf(x.w);
  }
  __syncthreads();
  int n = t >> 2, kc = (t & 3) * 16;
  u16x8 o0, o1;
#pragma unroll
  for (int j = 0; j < 8; ++j) { o0[j] = tile[kc + j][n]; o1[j] = tile[kc + 8 + j][n]; }
  u16* dst = (z < 3) ? (wcatT + (size_t)z * 1048576 + (size_t)(n0 + n) * 1024 + k0 + kc)
                     : (woT + (size_t)(n0 + n) * 1024 + k0 + kc);
  *(u16x8*)dst = o0;
  *(u16x8*)(dst + 8) = o1;
}

// ---------------- 3. GEMM mode0: QKV proj, 128x128 tile, BK=32, 8 waves -----
// 512 threads / 8 waves (wave tile 32x64): same grid 768 -> 24 waves/CU
// (was 12) to cover the barrier drains. A read fp32 direct (cvt fused),
// reg-staged with swizzle; B via global_load_lds.
__global__ __launch_bounds__(512) void gemm_bt(const float* __restrict__ Aq,
                                               const float* __restrict__ Ak,
                                               const float* __restrict__ Av,
                                               const u16* __restrict__ BT,
                                               u16* __restrict__ outBF,
                                               const float* __restrict__ b0,
                                               const float* __restrict__ b1,
                                               const float* __restrict__ b2) {
  __shared__ u16 As[2][4096];
  __shared__ u16 Bs[2][4096];
  int tid = threadIdx.x;
  int bid = blockIdx.y * 8 + blockIdx.x;
  int cpx = gridDim.y;
  int swz = (bid & 7) * cpx + (bid >> 3);
  int m0 = (swz >> 3) * 128, n0 = (swz & 7) * 128;
  int sec = m0 >> 12;                     // block-uniform section
  const float* A32 = sec == 0 ? Aq : sec == 1 ? Ak : Av;
  int mbase = m0 & 4095;
  const u16* bt = BT + (size_t)sec * 1048576;
  int w = tid >> 6, l = tid & 63;
  int wr = w >> 1, wc = w & 1;            // wave tile 32x64
  f32x4 acc[2][4];
#pragma unroll
  for (int i = 0; i < 2; ++i)
#pragma unroll
    for (int j = 0; j < 4; ++j)
#pragma unroll
      for (int rr = 0; rr < 4; ++rr) acc[i][j][rr] = 0.f;

  // per-thread staging addressing (swizzled source, rule #21); 512 thr cover
  // the 128x32 tile with 32B (A, fp32) / 16B (B, bf16) each
  int rS = tid >> 2, cpS = tid & 3;
  int clS = cpS ^ ((rS ^ (rS >> 2)) & 3);
  const float* srcA = A32 + (size_t)(mbase + rS) * 1024 + clS * 8;
  const u16* srcB = bt + (size_t)(n0 + rS) * 1024 + clS * 8;
  int dstS = tid * 8;
  float4 pa, pb4;
  auto loadA = [&](int kt) {
    pa = *(const float4*)(srcA + kt * 32);
    pb4 = *(const float4*)(srcA + kt * 32 + 4);
  };
  auto writeA = [&](int buf) {
    u16x8 o;
    o[0] = f2bf(pa.x); o[1] = f2bf(pa.y); o[2] = f2bf(pa.z); o[3] = f2bf(pa.w);
    o[4] = f2bf(pb4.x); o[5] = f2bf(pb4.y); o[6] = f2bf(pb4.z); o[7] = f2bf(pb4.w);
    *(u16x8*)&As[buf][dstS] = o;
  };
  auto stageB = [&](int buf, int kt) {
    gl_lds16(srcB + kt * 32, &Bs[buf][dstS]);
  };
  loadA(0);
  stageB(0, 0);
  writeA(0);
  __syncthreads();
  int sw = (l & 3) ^ ((l >> 2) & 3);
  int phys = (l >> 4) ^ sw;
  for (int kt = 0; kt < 32; ++kt) {
    int buf = kt & 1;
    if (kt < 31) {
      loadA(kt + 1);
      stageB(buf ^ 1, kt + 1);
    }
    bf16x8 af[2], bfr[4];
#pragma unroll
    for (int mi = 0; mi < 2; ++mi) {
      int row = wr * 32 + mi * 16 + (l & 15);
      af[mi] = *(const bf16x8*)&As[buf][row * 32 + phys * 8];
    }
#pragma unroll
    for (int nj = 0; nj < 4; ++nj) {
      int rowb = wc * 64 + nj * 16 + (l & 15);
      bfr[nj] = *(const bf16x8*)&Bs[buf][rowb * 32 + phys * 8];
    }
#pragma unroll
    for (int mi = 0; mi < 2; ++mi)
#pragma unroll
      for (int nj = 0; nj < 4; ++nj)
        acc[mi][nj] = __builtin_amdgcn_mfma_f32_16x16x32_bf16(af[mi], bfr[nj],
                                                              acc[mi][nj], 0, 0, 0);
    if (kt < 31) writeA(buf ^ 1);
    __syncthreads();
  }
  const float* bp = sec == 0 ? b0 : sec == 1 ? b1 : b2;
#pragma unroll
  for (int mi = 0; mi < 2; ++mi)
#pragma unroll
    for (int nj = 0; nj < 4; ++nj)
#pragma unroll
      for (int rr = 0; rr < 4; ++rr) {
        int orow = mbase + wr * 32 + mi * 16 + (l >> 4) * 4 + rr;
        int col = n0 + wc * 64 + nj * 16 + (l & 15);
        float vv = acc[mi][nj][rr] + bp[col];
        if (sec == 0) vv *= Q_SCALE;   // fold 1/(8*ln2) into Q (exp2 softmax)
        outBF[(size_t)sec * 4194304 + (size_t)orow * 1024 + col] = f2bf(vv);
      }
}

// ---------------- 6. GEMM mode1: O-proj, 128x64 tile, 8 waves ---------------
// 512 threads / 8 waves (wave tile 32x32): 2 blocks/CU -> 16 waves/CU (was 8).
__global__ __launch_bounds__(512) void gemm_n64(const u16* __restrict__ A,
                                                const u16* __restrict__ BT,
                                                float* __restrict__ outF,
                                                const float* __restrict__ b0,
                                                const float* __restrict__ resid) {
  __shared__ u16 As[2][4096];
  __shared__ u16 Bs[2][2048];
  int tid = threadIdx.x;
  int bid = blockIdx.y * 8 + blockIdx.x;   // grid (8,64) = 512
  int swz = (bid & 7) * 64 + (bid >> 3);   // XCD chunk of 64
  int m0 = (swz >> 4) * 128, n0 = (swz & 15) * 64;
  int w = tid >> 6, l = tid & 63;
  int wr = w >> 1, wc = w & 1;             // wave tile 32x32
  f32x4 acc[2][2];
#pragma unroll
  for (int i = 0; i < 2; ++i)
#pragma unroll
    for (int j = 0; j < 2; ++j)
#pragma unroll
      for (int rr = 0; rr < 4; ++rr) acc[i][j][rr] = 0.f;

  int rS = tid >> 2, cpS = tid & 3;
  int clS = cpS ^ ((rS ^ (rS >> 2)) & 3);
  const u16* srcA = A + (size_t)(m0 + rS) * 1024 + clS * 8;
  const u16* srcB = BT + (size_t)(n0 + rS) * 1024 + clS * 8;  // rS<64 only
  int dstS = tid * 8;
  auto stage = [&](int buf, int kt) {
    gl_lds16(srcA + kt * 32, &As[buf][dstS]);
    if (tid < 256) gl_lds16(srcB + kt * 32, &Bs[buf][dstS]);
  };
  stage(0, 0);
  __syncthreads();
  int sw = (l & 3) ^ ((l >> 2) & 3);
  int phys = (l >> 4) ^ sw;
  for (int kt = 0; kt < 32; ++kt) {
    int buf = kt & 1;
    if (kt < 31) stage(buf ^ 1, kt + 1);
    bf16x8 af[2], bfr[2];
#pragma unroll
    for (int mi = 0; mi < 2; ++mi) {
      int row = wr * 32 + mi * 16 + (l & 15);
      af[mi] = *(const bf16x8*)&As[buf][row * 32 + phys * 8];
    }
#pragma unroll
    for (int nj = 0; nj < 2; ++nj) {
      int rowb = wc * 32 + nj * 16 + (l & 15);
      bfr[nj] = *(const bf16x8*)&Bs[buf][rowb * 32 + phys * 8];
    }
#pragma unroll
    for (int mi = 0; mi < 2; ++mi)
#pragma unroll
      for (int nj = 0; nj < 2; ++nj)
        acc[mi][nj] = __builtin_amdgcn_mfma_f32_16x16x32_bf16(af[mi], bfr[nj],
                                                              acc[mi][nj], 0, 0, 0);
    __syncthreads();
  }
#pragma unroll
  for (int mi = 0; mi < 2; ++mi)
#pragma unroll
    for (int nj = 0; nj < 2; ++nj)
#pragma unroll
      for (int rr = 0; rr < 4; ++rr) {
        int row = m0 + wr * 32 + mi * 16 + (l >> 4) * 4 + rr;
        int col = n0 + wc * 32 + nj * 16 + (l & 15);
        outF[(size_t)row * 1024 + col] =
            acc[mi][nj][rr] + b0[col] + resid[(size_t)row * 1024 + col];
      }
}

// ---------------- 4. V transpose per head: vp[n][h*64+d] -> vt[h][d][n] ----
__global__ __launch_bounds__(256) void vtrans_kernel(const u16* __restrict__ vp,
                                                     u16* __restrict__ vt) {
  __shared__ u16 tile[64][72];
  int t = threadIdx.x;
  int n0 = blockIdx.x * 64, h = blockIdx.y;
  int r = t >> 2, c0 = (t & 3) * 16;
  u16x8 a = *(const u16x8*)(vp + (size_t)(n0 + r) * 1024 + h * 64 + c0);
  u16x8 b = *(const u16x8*)(vp + (size_t)(n0 + r) * 1024 + h * 64 + c0 + 8);
#pragma unroll
  for (int j = 0; j < 8; ++j) { tile[r][c0 + j] = a[j]; tile[r][c0 + 8 + j] = b[j]; }
  __syncthreads();
  int d = t >> 2, nc = (t & 3) * 16;
  u16x8 o0, o1;
#pragma unroll
  for (int j = 0; j < 8; ++j) { o0[j] = tile[nc + j][d]; o1[j] = tile[nc + 8 + j][d]; }
  size_t base = (size_t)(h * 64 + d) * 4096 + n0 + nc;
  *(u16x8*)(vt + base) = o0;
  *(u16x8*)(vt + base + 8) = o1;
}

// ---------------- 5. flash attention, intra-block KV split (frozen) --------
__global__ __launch_bounds__(512, 4) void attn_kernel(const u16* __restrict__ qp,
                                                      const u16* __restrict__ kp,
                                                      const u16* __restrict__ vt,
                                                      u16* __restrict__ attout) {
  __shared__ u16 smem[32768];  // 64KB: [half][buf][K 4KB | VT 4KB]
  int tid = threadIdx.x;
  int w = tid >> 6, l = tid & 63;
  int half = w >> 2, wl = w & 3;
  int hi = l >> 5, l31 = l & 31;
  int h = blockIdx.y, bx = blockIdx.x;
  int qrow = bx * 128 + wl * 32 + l31;
  bf16x8 qf[4];
#pragma unroll
  for (int ds = 0; ds < 4; ++ds)
    qf[ds] = *(const bf16x8*)(qp + (size_t)qrow * 1024 + h * 64 + ds * 16 + hi * 8);

  f32x16 zero16;
#pragma unroll
  for (int r = 0; r < 16; ++r) zero16[r] = 0.f;
  f32x16 accO[2];
#pragma unroll
  for (int r = 0; r < 16; ++r) { accO[0][r] = 0.f; accO[1][r] = 0.f; }
  float l_run = 0.f;

  u16* sbase = smem + half * 16384;
  int ht = (wl << 6) | l;  // half-local thread id, 0..255
  const u16* srcK[2]; const u16* srcV[2]; int dstOff[2];
#pragma unroll
  for (int i = 0; i < 2; ++i) {
    int id = i * 256 + ht;
    int r = id >> 3, cp = id & 7;
    int cl = cp ^ ((r ^ (r >> 3)) & 7);  // inverse swizzle on source (rule #21)
    srcK[i] = kp + (size_t)(half * 2048 + r) * 1024 + h * 64 + cl * 8;
    srcV[i] = vt + (size_t)(h * 64 + r) * 4096 + half * 2048 + cl * 8;
    dstOff[i] = id * 8;
  }
  auto stage = [&](int buf, int kt) {
    u16* b = sbase + buf * 8192;
#pragma unroll
    for (int i = 0; i < 2; ++i) {
      gl_lds16(srcK[i] + (size_t)kt * 65536, b + dstOff[i]);
      gl_lds16(srcV[i] + kt * 64, b + 4096 + dstOff[i]);
    }
  };
  stage(0, 0);
  __syncthreads();

  for (int kt = 0; kt < 32; ++kt) {
    int buf = kt & 1;
    if (kt < 31) stage(buf ^ 1, kt + 1);
    const u16* Kt = sbase + buf * 8192;
    const u16* Vt = Kt + 4096;

    // S^T = K @ Q^T (rows kv, cols q), log2 domain (Q pre-scaled)
    f32x16 accS[2];
    __builtin_amdgcn_s_setprio(1);
#pragma unroll
    for (int mt = 0; mt < 2; ++mt) {
      int row = mt * 32 + l31;
      int g = (row ^ (row >> 3)) & 7;
      {
        bf16x8 kf = *(const bf16x8*)(Kt + row * 64 + ((0 + hi) ^ g) * 8);
        accS[mt] = __builtin_amdgcn_mfma_f32_32x32x16_bf16(kf, qf[0], zero16, 0, 0, 0);
      }
#pragma unroll
      for (int ds = 1; ds < 4; ++ds) {
        int phys = (2 * ds + hi) ^ g;
        bf16x8 kf = *(const bf16x8*)(Kt + row * 64 + phys * 8);
        accS[mt] = __builtin_amdgcn_mfma_f32_32x32x16_bf16(kf, qf[ds], accS[mt], 0, 0, 0);
      }
    }
    __builtin_amdgcn_s_setprio(0);

    // p = exp2(s) directly; l partials on VALU; cross-lane shfl deferred
    u32 pku[2][8];
    float s0 = 0.f, s1 = 0.f, s2 = 0.f, s3 = 0.f;
#pragma unroll
    for (int mt = 0; mt < 2; ++mt)
#pragma unroll
      for (int qd = 0; qd < 8; ++qd) {
        float a = ex2(accS[mt][2 * qd]);
        float b = ex2(accS[mt][2 * qd + 1]);
        if (qd & 1) { s2 += a; s3 += b; } else { s0 += a; s1 += b; }
        pku[mt][qd] = pack2(a, b);
      }
    l_run += (s0 + s1) + (s2 + s3);

    // assemble P^T B-frags via permlane32_swap (A_hi <-> B_lo):
    bf16x8 pb[4];
#pragma unroll
    for (int ks = 0; ks < 4; ++ks) {
      const int mt = ks >> 1, k1 = ks & 1;
      u32 a0 = pku[mt][4 * k1 + 0], c0 = pku[mt][4 * k1 + 2];
      u32 a1 = pku[mt][4 * k1 + 1], c1 = pku[mt][4 * k1 + 3];
      asm("v_permlane32_swap_b32 %0, %1" : "+v"(a0), "+v"(c0));
      asm("v_permlane32_swap_b32 %0, %1" : "+v"(a1), "+v"(c1));
      u32x4 fr;
      fr[0] = a0; fr[1] = a1; fr[2] = c0; fr[3] = c1;
      pb[ks] = __builtin_bit_cast(bf16x8, fr);
    }
    // O^T += V^T @ P^T
    __builtin_amdgcn_s_setprio(1);
#pragma unroll
    for (int mto = 0; mto < 2; ++mto) {
      int row = mto * 32 + l31;
      int g = (row ^ (row >> 3)) & 7;
#pragma unroll
      for (int ks = 0; ks < 4; ++ks) {
        int phys = (2 * ks + hi) ^ g;
        bf16x8 vf = *(const bf16x8*)(Vt + row * 64 + phys * 8);
        accO[mto] = __builtin_amdgcn_mfma_f32_32x32x16_bf16(vf, pb[ks], accO[mto], 0, 0, 0);
      }
    }
    __builtin_amdgcn_s_setprio(0);
    __syncthreads();
  }
  l_run += __shfl_xor(l_run, 32, 64);   // deferred cross-lane l reduce

  // -------- cross-half combine: O = (O_A + O_B) / (l_A + l_B) --------
  u16* pO = smem;
  float* ml = (float*)(smem + 2 * 128 * 72);
  int q = wl * 32 + l31;
#pragma unroll
  for (int mto = 0; mto < 2; ++mto)
#pragma unroll
    for (int g = 0; g < 4; ++g)
#pragma unroll
      for (int j = 0; j < 2; ++j) {
        int r = g * 4 + j * 2;
        int d = j * 2 + 8 * g + 4 * hi + 32 * mto;
        u32 pk = pack2(accO[mto][r], accO[mto][r + 1]);
        *(u32*)&pO[(size_t)(half * 128 + q) * 72 + d] = pk;
      }
  if (hi == 0) ml[half * 128 + q] = l_run;
  __syncthreads();
  {
    int qq = tid >> 2, d0 = (tid & 3) * 16;   // 512 thr x 16 cols = 128x64
    float invL = 1.f / (ml[qq] + ml[128 + qq]);
    u16x8 ra0 = *(u16x8*)&pO[(size_t)qq * 72 + d0];
    u16x8 ra1 = *(u16x8*)&pO[(size_t)qq * 72 + d0 + 8];
    u16x8 rb0 = *(u16x8*)&pO[(size_t)(128 + qq) * 72 + d0];
    u16x8 rb1 = *(u16x8*)&pO[(size_t)(128 + qq) * 72 + d0 + 8];
    u16x8 o0, o1;
#pragma unroll
    for (int j = 0; j < 8; ++j) {
      o0[j] = f2bf((bf2f(ra0[j]) + bf2f(rb0[j])) * invL);
      o1[j] = f2bf((bf2f(ra1[j]) + bf2f(rb1[j])) * invL);
    }
    size_t ob = (size_t)(bx * 128 + qq) * 1024 + (size_t)h * 64 + d0;
    *(u16x8*)(attout + ob) = o0;
    *(u16x8*)(attout + ob + 8) = o1;
  }
}

// ---------------- 7. LayerNorm in-place on d_out ----------------------------
__global__ __launch_bounds__(256) void ln_kernel(float* __restrict__ io,
                                                 const float* __restrict__ gamma,
                                                 const float* __restrict__ beta) {
  int row = blockIdx.x, t = threadIdx.x;
  float4 v = *(const float4*)(io + (size_t)row * 1024 + t * 4);
  float s = v.x + v.y + v.z + v.w;
  float sq = v.x * v.x + v.y * v.y + v.z * v.z + v.w * v.w;
#pragma unroll
  for (int off = 1; off < 64; off <<= 1) {
    s += __shfl_xor(s, off, 64);
    sq += __shfl_xor(sq, off, 64);
  }
  __shared__ float rs[4], rq[4];
  if ((t & 63) == 0) { rs[t >> 6] = s; rq[t >> 6] = sq; }
  __syncthreads();
  float S = rs[0] + rs[1] + rs[2] + rs[3];
  float Q = rq[0] + rq[1] + rq[2] + rq[3];
  float mu = S * (1.f / 1024.f);
  float var = Q * (1.f / 1024.f) - mu * mu;
  float invs = rsqrtf(var + 1e-12f);
  float4 g = *(const float4*)(gamma + t * 4);
  float4 b = *(const float4*)(beta + t * 4);
  float4 o;
  o.x = (v.x - mu) * invs * g.x + b.x;
  o.y = (v.y - mu) * invs * g.y + b.y;
  o.z = (v.z - mu) * invs * g.z + b.z;
  o.w = (v.w - mu) * invs * g.w + b.w;
  *(float4*)(io + (size_t)row * 1024 + t * 4) = o;
}

extern "C" void kernel_launch(void* const* d_in, const int* in_sizes, int n_in,
                              void* d_out, int out_size, void* d_ws, size_t ws_size,
                              hipStream_t stream) {
  (void)in_sizes; (void)n_in; (void)out_size; (void)ws_size;
  const float* queries = (const float*)d_in[0];
  const float* keys    = (const float*)d_in[1];
  const float* values  = (const float*)d_in[2];
  const float* Wq = (const float*)d_in[3];
  const float* bq = (const float*)d_in[4];
  const float* Wk = (const float*)d_in[5];
  const float* bk = (const float*)d_in[6];
  const float* Wv = (const float*)d_in[7];
  const float* bv = (const float*)d_in[8];
  const float* Wo = (const float*)d_in[9];
  const float* bo = (const float*)d_in[10];
  const float* gamma = (const float*)d_in[11];
  const float* beta  = (const float*)d_in[12];
  float* out = (float*)d_out;

  u16* ws = (u16*)d_ws;
  u16* attout = ws;                 // 4096x1024
  u16* vt     = ws + 4194304;       // [16][64][4096]
  u16* wcatT  = ws + 12582912;      // 3x 1024x1024
  u16* woT    = ws + 15728640;      // 1024x1024
  u16* qp     = ws + 16777216;      // q,k,v projections contiguous
  u16* kp     = qp + 4194304;
  u16* vp     = qp + 8388608;

  prep_kernel<<<dim3(16, 16, 4), dim3(256), 0, stream>>>(Wq, Wk, Wv, Wo, wcatT, woT);
  gemm_bt<<<dim3(8, 96), dim3(512), 0, stream>>>(queries, keys, values, wcatT, qp,
                                                 bq, bk, bv);
  vtrans_kernel<<<dim3(64, 16), dim3(256), 0, stream>>>(vp, vt);
  attn_kernel<<<dim3(32, 16), dim3(512), 0, stream>>>(qp, kp, vt, attout);
  gemm_n64<<<dim3(8, 64), dim3(512), 0, stream>>>(attout, woT, out, bo, queries);
  ln_kernel<<<dim3(4096), dim3(256), 0, stream>>>(out, gamma, beta);
}